// Round 13
// baseline (104.136 us; speedup 1.0000x reference)
//
#include <hip/hip_runtime.h>
#include <hip/hip_bf16.h>
#include <hip/hip_fp16.h>
#include <math.h>

// Problem constants
#define NB   2
#define CC   256
#define HH   128
#define WW   128
#define HPP  130
#define WPP  130
#define LQ   16384   // HH*WW

typedef __attribute__((ext_vector_type(8))) short short8;
typedef __attribute__((ext_vector_type(8))) unsigned short u16x8;
typedef __attribute__((ext_vector_type(4))) float f32x4;
typedef __attribute__((ext_vector_type(4))) unsigned int u32x4;

static __device__ __forceinline__ unsigned short f2bf(float f) {
    __hip_bfloat16 h = __float2bfloat16(f);
    return __builtin_bit_cast(unsigned short, h);
}
static __device__ __forceinline__ float bf2f(unsigned short u) {
    unsigned int x = ((unsigned int)u) << 16;
    return __builtin_bit_cast(float, x);
}
// packed f32x2 -> f16x2 (v_cvt_pkrtz_f16_f32, 1 VALU op)
static __device__ __forceinline__ __half2 f22h2(float2 f) {
    auto r = __builtin_amdgcn_cvt_pkrtz(f.x, f.y);  // __fp16 ext_vector(2)
    return __builtin_bit_cast(__half2, r);
}

// branch-free tanh-form GELU: x * sigmoid(1.5957691*(x + 0.044715 x^3))
static __device__ __forceinline__ float gelu_fast(float x) {
    float u = x * x;
    float t = x * fmaf(0.044715f, u, 1.0f);
    float e = __builtin_amdgcn_exp2f(t * 2.3022083f);
    float r = __builtin_amdgcn_rcpf(e + 1.0f);
    return x - x * r;
}

// ---- DPP wave-64 sum reduction (VALU pipe, no LDS) ---------------------
// Template params so the DPP immediates are integer constant expressions.
template <int CTRL, int RMASK, int BMASK>
static __device__ __forceinline__ float dpp_add(float x) {
    int s = __builtin_bit_cast(int, x);
    int d = __builtin_amdgcn_update_dpp(0, s, CTRL, RMASK, BMASK, true);
    return x + __builtin_bit_cast(float, d);
}
static __device__ __forceinline__ float wave_sum_lane63(float x) {
    x = dpp_add<0x111, 0xf, 0xf>(x);   // row_shr:1
    x = dpp_add<0x112, 0xf, 0xf>(x);   // row_shr:2
    x = dpp_add<0x114, 0xf, 0xe>(x);   // row_shr:4  bank_mask 0xe
    x = dpp_add<0x118, 0xf, 0xc>(x);   // row_shr:8  bank_mask 0xc
    x = dpp_add<0x142, 0xa, 0xf>(x);   // row_bcast:15 row_mask 0xa
    x = dpp_add<0x143, 0xc, 0xf>(x);   // row_bcast:31 row_mask 0xc
    return x;                          // valid in lane 63
}

// -------------------------------------------------------------------------
// Kernel A: merged weight prep + v_pad border zeroing (no query convert).
// -------------------------------------------------------------------------
__global__ __launch_bounds__(256) void prep_kernel(
    const float* __restrict__ dwk,
    const float* __restrict__ Wval,
    const float* __restrict__ Wout,
    const float* __restrict__ Woff, const float* __restrict__ boff,
    const float* __restrict__ Wattn, const float* __restrict__ battn,
    __half* __restrict__ kth,
    unsigned short* __restrict__ wt_val,
    unsigned short* __restrict__ wt_out,
    unsigned short* __restrict__ wt_oa,
    float* __restrict__ b_oa,
    unsigned short* __restrict__ vpad)
{
    int b = blockIdx.x;
    int t = threadIdx.x;
    if (b < 49) {
        kth[b * CC + t] = __float2half(dwk[t * 49 + b]);
    } else if (b < 305) {
        int k = b - 49;
        wt_val[(size_t)t * 256 + k] = f2bf(Wval[(size_t)k * 256 + t]);
    } else if (b < 561) {
        int k = b - 305;
        wt_out[(size_t)t * 256 + k] = f2bf(Wout[(size_t)k * 256 + t]);
    } else if (b < 817) {
        int k = b - 561;
        if (t < 128) {
            float v = 0.f, bb = 0.f;
            if (t < 64)      { v = Woff[(size_t)k * 64 + t];        bb = boff[t]; }
            else if (t < 96) { v = Wattn[(size_t)k * 32 + (t - 64)]; bb = battn[t - 64]; }
            wt_oa[(size_t)t * 256 + k] = f2bf(v);
            if (k == 0) b_oa[t] = bb;
        }
    } else {
        int bb = b - 817;
        int n = (bb >= 516) ? 1 : 0;
        int i = bb - n * 516;
        int y, x;
        if (i < 130)      { y = 0;           x = i; }
        else if (i < 260) { y = 129;         x = i - 130; }
        else if (i < 388) { y = i - 260 + 1; x = 0; }
        else              { y = i - 388 + 1; x = 129; }
        vpad[(((size_t)n * HPP + y) * WPP + x) * CC + t] = 0;
    }
}

// -------------------------------------------------------------------------
// Kernel 1: fused depthwise 7x7 conv (fp16x2 packed) + bias + channel-LN
// + GELU -> bf16.  Reads fp32 query directly (float2 load + cvt_pkrtz).
// Block = 128 threads (2 waves); thread = channel PAIR, 8 w-positions.
// LN reduce on the VALU via DPP (no DS-pipe shuffles).
// -------------------------------------------------------------------------
__global__ __launch_bounds__(128) void conv_ln_gelu_kernel(
    const float* __restrict__ q,      // (N, LQ, C) fp32
    const __half* __restrict__ kth,   // (49, C) fp16
    const float* __restrict__ kbias,
    const float* __restrict__ lnw,
    const float* __restrict__ lnb,
    unsigned short* __restrict__ qact) // (N, LQ, C) bf16
{
    int t  = threadIdx.x;             // 0..127 -> channels 2t, 2t+1
    int w0 = blockIdx.x * 8;
    int h  = blockIdx.y;
    int n  = blockIdx.z;

    const float2*  qn  = reinterpret_cast<const float2*>(q) + (size_t)n * LQ * 128 + t;
    const __half2* ktc = reinterpret_cast<const __half2*>(kth) + t;

    __half2 acc[8];
    #pragma unroll
    for (int i = 0; i < 8; ++i) acc[i] = __half2(0.f, 0.f);

    if (w0 >= 8 && w0 <= 112 && h >= 3 && h <= 124) {
        #pragma unroll
        for (int ky = 0; ky < 7; ++ky) {
            const float2* qrow = qn + ((size_t)(h + ky - 3) * WW + (w0 - 3)) * 128;
            __half2 wt[7];
            #pragma unroll
            for (int kx = 0; kx < 7; ++kx)
                wt[kx] = ktc[(ky * 7 + kx) * 128];
            __half2 in[14];
            #pragma unroll
            for (int j = 0; j < 14; ++j)
                in[j] = f22h2(qrow[(size_t)j * 128]);
            #pragma unroll
            for (int i = 0; i < 8; ++i)
                #pragma unroll
                for (int kx = 0; kx < 7; ++kx)
                    acc[i] = __hfma2(in[i + kx], wt[kx], acc[i]);
        }
    } else {
        #pragma unroll
        for (int ky = 0; ky < 7; ++ky) {
            int iy = h + ky - 3;
            if (iy < 0 || iy >= HH) continue;
            const float2* qrow = qn + (size_t)iy * WW * 128;
            __half2 wt[7];
            #pragma unroll
            for (int kx = 0; kx < 7; ++kx)
                wt[kx] = ktc[(ky * 7 + kx) * 128];
            __half2 in[14];
            #pragma unroll
            for (int j = 0; j < 14; ++j) {
                int ix = w0 - 3 + j;
                in[j] = (ix >= 0 && ix < WW) ? f22h2(qrow[(size_t)ix * 128])
                                             : __half2(0.f, 0.f);
            }
            #pragma unroll
            for (int i = 0; i < 8; ++i)
                #pragma unroll
                for (int kx = 0; kx < 7; ++kx)
                    acc[i] = __hfma2(in[i + kx], wt[kx], acc[i]);
        }
    }

    float b0 = kbias[2 * t];
    float b1 = kbias[2 * t + 1];
    float a0[8], a1[8];
    #pragma unroll
    for (int i = 0; i < 8; ++i) {
        a0[i] = __low2float(acc[i])  + b0;
        a1[i] = __high2float(acc[i]) + b1;
    }

    // LayerNorm stats: DPP wave-reduce (VALU), combine 2 waves via LDS
    __shared__ float lsum[8][2];
    __shared__ float lsq[8][2];
    int lane = t & 63;
    int wv   = t >> 6;

    #pragma unroll
    for (int i = 0; i < 8; ++i) {
        float s  = wave_sum_lane63(a0[i] + a1[i]);
        float sq = wave_sum_lane63(a0[i] * a0[i] + a1[i] * a1[i]);
        if (lane == 63) { lsum[i][wv] = s; lsq[i][wv] = sq; }
    }
    __syncthreads();

    float lw0 = lnw[2 * t], lw1 = lnw[2 * t + 1];
    float lb0 = lnb[2 * t], lb1 = lnb[2 * t + 1];
    unsigned short* qo = qact + (((size_t)n * LQ) + (size_t)h * WW + w0) * CC + 2 * t;

    #pragma unroll
    for (int i = 0; i < 8; ++i) {
        float s   = lsum[i][0] + lsum[i][1];
        float sq  = lsq[i][0]  + lsq[i][1];
        float mu  = s * (1.0f / 256.0f);
        float var = sq * (1.0f / 256.0f) - mu * mu;
        float inv = rsqrtf(var + 1e-5f);
        float g0 = gelu_fast((a0[i] - mu) * inv * lw0 + lb0);
        float g1 = gelu_fast((a1[i] - mu) * inv * lw1 + lb1);
        ushort2 o;
        o.x = f2bf(g0);
        o.y = f2bf(g1);
        *reinterpret_cast<ushort2*>(qo + (size_t)i * CC) = o;
    }
}

// -------------------------------------------------------------------------
// Kernel 2a: merged value + oa GEMM (bf16 MFMA), grid.y: 0,1=val  2=oa
// -------------------------------------------------------------------------
__global__ __launch_bounds__(256) void gemm_val_oa(
    const unsigned short* __restrict__ A,
    const unsigned short* __restrict__ Bv, const float* __restrict__ bv_,
    unsigned short* __restrict__ Cv,
    const unsigned short* __restrict__ Bo, const float* __restrict__ bo_,
    float* __restrict__ Co)
{
    __shared__ unsigned short Al[128][72];
    __shared__ unsigned short Bl[128][72];

    bool oam = (blockIdx.y == 2);
    const unsigned short* Bt = oam ? Bo : Bv;
    const float* bias = oam ? bo_ : bv_;
    int bn = oam ? 0 : blockIdx.y * 128;

    int t    = threadIdx.x;
    int bm   = blockIdx.x * 128;
    int wid  = t >> 6;
    int lane = t & 63;
    int wr   = wid >> 1;
    int wc   = wid & 1;
    int lr   = lane & 15;
    int lg   = lane >> 4;

    int srow = t >> 1;
    int sseg = (t & 1) << 5;

    const unsigned short* gA = A + (size_t)(bm + srow) * 256 + sseg;
    const unsigned short* gB = Bt + (size_t)(bn + srow) * 256 + sseg;
    unsigned short* lA = &Al[srow][sseg];
    unsigned short* lB = &Bl[srow][sseg];

    f32x4 acc[4][4] = {};

    for (int kt = 0; kt < 4; ++kt) {
        const unsigned short* ga = gA + kt * 64;
        const unsigned short* gb = gB + kt * 64;
        u32x4 a0 = *(const u32x4*)(ga);
        u32x4 a1 = *(const u32x4*)(ga + 8);
        u32x4 a2 = *(const u32x4*)(ga + 16);
        u32x4 a3 = *(const u32x4*)(ga + 24);
        u32x4 b0 = *(const u32x4*)(gb);
        u32x4 b1 = *(const u32x4*)(gb + 8);
        u32x4 b2 = *(const u32x4*)(gb + 16);
        u32x4 b3 = *(const u32x4*)(gb + 24);
        *(u32x4*)(lA)      = a0;
        *(u32x4*)(lA + 8)  = a1;
        *(u32x4*)(lA + 16) = a2;
        *(u32x4*)(lA + 24) = a3;
        *(u32x4*)(lB)      = b0;
        *(u32x4*)(lB + 8)  = b1;
        *(u32x4*)(lB + 16) = b2;
        *(u32x4*)(lB + 24) = b3;
        __syncthreads();

        #pragma unroll
        for (int kk = 0; kk < 2; ++kk) {
            short8 af[4], bfr[4];
            #pragma unroll
            for (int m = 0; m < 4; ++m)
                af[m] = *(const short8*)(&Al[wr * 64 + m * 16 + lr][kk * 32 + lg * 8]);
            #pragma unroll
            for (int nn = 0; nn < 4; ++nn)
                bfr[nn] = *(const short8*)(&Bl[wc * 64 + nn * 16 + lr][kk * 32 + lg * 8]);
            #pragma unroll
            for (int m = 0; m < 4; ++m)
                #pragma unroll
                for (int nn = 0; nn < 4; ++nn)
                    acc[m][nn] = __builtin_amdgcn_mfma_f32_16x16x32_bf16(
                        af[m], bfr[nn], acc[m][nn], 0, 0, 0);
        }
        __syncthreads();
    }

    float bvv[4];
    #pragma unroll
    for (int nn = 0; nn < 4; ++nn) bvv[nn] = bias[bn + wc * 64 + nn * 16 + lr];

    #pragma unroll
    for (int m = 0; m < 4; ++m) {
        #pragma unroll
        for (int j = 0; j < 4; ++j) {
            int row = bm + wr * 64 + m * 16 + lg * 4 + j;
            if (oam) {
                size_t rbase = (size_t)row * 128;
                #pragma unroll
                for (int nn = 0; nn < 4; ++nn) {
                    int col = wc * 64 + nn * 16 + lr;
                    Co[rbase + col] = acc[m][nn][j] + bvv[nn];
                }
            } else {
                int nb = row >> 14;
                int hw = row & 16383;
                int hh = hw >> 7;
                int ww = hw & 127;
                size_t rbase = (((size_t)nb * HPP + (hh + 1)) * WPP + (ww + 1)) * CC;
                #pragma unroll
                for (int nn = 0; nn < 4; ++nn) {
                    int col = bn + wc * 64 + nn * 16 + lr;
                    Cv[rbase + col] = f2bf(acc[m][nn][j] + bvv[nn]);
                }
            }
        }
    }
}

// -------------------------------------------------------------------------
// Kernel 2b: bf16 MFMA GEMM, row-major fp32 store (output GEMM)
// -------------------------------------------------------------------------
__global__ __launch_bounds__(256) void gemm_mfma_row(
    const unsigned short* __restrict__ A,
    const unsigned short* __restrict__ Bt,
    const float* __restrict__ bias,
    float* __restrict__ C,
    int Nn)
{
    __shared__ unsigned short Al[128][72];
    __shared__ unsigned short Bl[128][72];

    int t    = threadIdx.x;
    int bm   = blockIdx.x * 128;
    int bn   = blockIdx.y * 128;
    int wid  = t >> 6;
    int lane = t & 63;
    int wr   = wid >> 1;
    int wc   = wid & 1;
    int lr   = lane & 15;
    int lg   = lane >> 4;

    int srow = t >> 1;
    int sseg = (t & 1) << 5;

    const unsigned short* gA = A + (size_t)(bm + srow) * 256 + sseg;
    const unsigned short* gB = Bt + (size_t)(bn + srow) * 256 + sseg;
    unsigned short* lA = &Al[srow][sseg];
    unsigned short* lB = &Bl[srow][sseg];

    f32x4 acc[4][4] = {};

    for (int kt = 0; kt < 4; ++kt) {
        const unsigned short* ga = gA + kt * 64;
        const unsigned short* gb = gB + kt * 64;
        u32x4 a0 = *(const u32x4*)(ga);
        u32x4 a1 = *(const u32x4*)(ga + 8);
        u32x4 a2 = *(const u32x4*)(ga + 16);
        u32x4 a3 = *(const u32x4*)(ga + 24);
        u32x4 b0 = *(const u32x4*)(gb);
        u32x4 b1 = *(const u32x4*)(gb + 8);
        u32x4 b2 = *(const u32x4*)(gb + 16);
        u32x4 b3 = *(const u32x4*)(gb + 24);
        *(u32x4*)(lA)      = a0;
        *(u32x4*)(lA + 8)  = a1;
        *(u32x4*)(lA + 16) = a2;
        *(u32x4*)(lA + 24) = a3;
        *(u32x4*)(lB)      = b0;
        *(u32x4*)(lB + 8)  = b1;
        *(u32x4*)(lB + 16) = b2;
        *(u32x4*)(lB + 24) = b3;
        __syncthreads();

        #pragma unroll
        for (int kk = 0; kk < 2; ++kk) {
            short8 af[4], bfr[4];
            #pragma unroll
            for (int m = 0; m < 4; ++m)
                af[m] = *(const short8*)(&Al[wr * 64 + m * 16 + lr][kk * 32 + lg * 8]);
            #pragma unroll
            for (int nn = 0; nn < 4; ++nn)
                bfr[nn] = *(const short8*)(&Bl[wc * 64 + nn * 16 + lr][kk * 32 + lg * 8]);
            #pragma unroll
            for (int m = 0; m < 4; ++m)
                #pragma unroll
                for (int nn = 0; nn < 4; ++nn)
                    acc[m][nn] = __builtin_amdgcn_mfma_f32_16x16x32_bf16(
                        af[m], bfr[nn], acc[m][nn], 0, 0, 0);
        }
        __syncthreads();
    }

    float bvv[4];
    #pragma unroll
    for (int nn = 0; nn < 4; ++nn) bvv[nn] = bias[bn + wc * 64 + nn * 16 + lr];

    #pragma unroll
    for (int m = 0; m < 4; ++m) {
        #pragma unroll
        for (int j = 0; j < 4; ++j) {
            int row = bm + wr * 64 + m * 16 + lg * 4 + j;
            size_t rbase = (size_t)row * Nn;
            #pragma unroll
            for (int nn = 0; nn < 4; ++nn) {
                int col = bn + wc * 64 + nn * 16 + lr;
                C[rbase + col] = acc[m][nn][j] + bvv[nn];
            }
        }
    }
}

// -------------------------------------------------------------------------
// Kernel 3: deformable bilinear sampling + attention-weighted sum
// 8 rows/block; phase 1: 256 threads = (8 rows x 8 heads x 4 points);
// phase 2: thread = 8 channels (ushort8 16B gathers), 32 threads/row.
// -------------------------------------------------------------------------
__global__ __launch_bounds__(256) void sampler_kernel(
    const float* __restrict__ rp,            // (N, LQ, 1, 2)
    const float* __restrict__ oa,            // (N*LQ, 128)
    const unsigned short* __restrict__ vpad, // (N, HP, WP, C) bf16
    unsigned short* __restrict__ outb)       // (N*LQ, C) bf16
{
    __shared__ int4   sIdx[8][4][8];
    __shared__ float4 sW[8][4][8];

    int tid  = threadIdx.x;
    int row0 = blockIdx.x * 8;

    {
        int rl   = tid >> 5;
        int hp   = tid & 31;
        int head = hp >> 2;
        int p    = hp & 3;
        int row  = row0 + rl;

        float ref0 = rp[(size_t)row * 2 + 0];
        float ref1 = rp[(size_t)row * 2 + 1];
        float o0 = oa[(size_t)row * 128 + head * 8 + p * 2 + 0];
        float o1 = oa[(size_t)row * 128 + head * 8 + p * 2 + 1];
        float al = oa[(size_t)row * 128 + 64 + head * 4 + p];
        float a  = 1.0f / (1.0f + __builtin_amdgcn_exp2f(-al * 1.4426950409f));

        float gy = (float)(p >> 1);
        float gx = (float)(p & 1);
        float x = ref0 * WPP + gy + o0 - 0.5f;
        float y = ref1 * HPP + gx + o1 - 0.5f;

        float x0f = floorf(x), y0f = floorf(y);
        int   x0  = (int)x0f,  y0  = (int)y0f;
        float wx1 = x - x0f, wx0 = 1.f - wx1;
        float wy1 = y - y0f, wy0 = 1.f - wy1;
        int x1 = x0 + 1, y1 = y0 + 1;

        bool vx0 = (x0 >= 0) & (x0 < WPP);
        bool vx1 = (x1 >= 0) & (x1 < WPP);
        bool vy0 = (y0 >= 0) & (y0 < HPP);
        bool vy1 = (y1 >= 0) & (y1 < HPP);
        int cx0 = min(max(x0, 0), WPP - 1);
        int cx1 = min(max(x1, 0), WPP - 1);
        int cy0 = min(max(y0, 0), HPP - 1);
        int cy1 = min(max(y1, 0), HPP - 1);

        int4 id;
        id.x = cy0 * WPP + cx0;
        id.y = cy0 * WPP + cx1;
        id.z = cy1 * WPP + cx0;
        id.w = cy1 * WPP + cx1;
        float4 w;
        w.x = (vx0 && vy0) ? a * wx0 * wy0 : 0.f;
        w.y = (vx1 && vy0) ? a * wx1 * wy0 : 0.f;
        w.z = (vx0 && vy1) ? a * wx0 * wy1 : 0.f;
        w.w = (vx1 && vy1) ? a * wx1 * wy1 : 0.f;

        sIdx[rl][p][head] = id;
        sW[rl][p][head]   = w;
    }
    __syncthreads();

    int rl   = tid >> 5;
    int c0   = (tid & 31) * 8;
    int head = (tid & 31) >> 2;
    int row  = row0 + rl;
    int n    = row >> 14;
    const unsigned short* vbase = vpad + (size_t)n * HPP * WPP * CC + c0;

    float acc[8] = {};
    #pragma unroll
    for (int p = 0; p < 4; ++p) {
        int4   id = sIdx[rl][p][head];
        float4 w  = sW[rl][p][head];
        u16x8 g0 = *reinterpret_cast<const u16x8*>(vbase + (size_t)id.x * CC);
        u16x8 g1 = *reinterpret_cast<const u16x8*>(vbase + (size_t)id.y * CC);
        u16x8 g2 = *reinterpret_cast<const u16x8*>(vbase + (size_t)id.z * CC);
        u16x8 g3 = *reinterpret_cast<const u16x8*>(vbase + (size_t)id.w * CC);
        #pragma unroll
        for (int j = 0; j < 8; ++j) {
            acc[j] += w.x * bf2f(g0[j]) + w.y * bf2f(g1[j])
                    + w.z * bf2f(g2[j]) + w.w * bf2f(g3[j]);
        }
    }
    u16x8 o;
    #pragma unroll
    for (int j = 0; j < 8; ++j) o[j] = f2bf(acc[j]);
    *reinterpret_cast<u16x8*>(&outb[(size_t)row * CC + c0]) = o;
}

// -------------------------------------------------------------------------
extern "C" void kernel_launch(void* const* d_in, const int* in_sizes, int n_in,
                              void* d_out, int out_size, void* d_ws, size_t ws_size,
                              hipStream_t stream)
{
    const float* query = (const float*)d_in[0];
    const float* rp    = (const float*)d_in[1];
    const float* dwk   = (const float*)d_in[4];
    const float* dwb   = (const float*)d_in[5];
    const float* lnw   = (const float*)d_in[6];
    const float* lnb   = (const float*)d_in[7];
    const float* Woff  = (const float*)d_in[8];
    const float* boff  = (const float*)d_in[9];
    const float* Wattn = (const float*)d_in[10];
    const float* battn = (const float*)d_in[11];
    const float* Wval  = (const float*)d_in[12];
    const float* bval  = (const float*)d_in[13];
    const float* Wout  = (const float*)d_in[14];
    const float* bout  = (const float*)d_in[15];
    float* out = (float*)d_out;

    const int M = NB * LQ;  // 32768

    // workspace layout (bytes)
    uint8_t* w8 = (uint8_t*)d_ws;
    unsigned short* q_act  = (unsigned short*)w8;                 // 16,777,216
    unsigned short* v_pad  = (unsigned short*)(w8 + 16777216);    // 17,305,600 (bf16)
    float*          oa     = (float*)(w8 + 34082816);             // 16,777,216
    unsigned short* wt_val = (unsigned short*)(w8 + 50860032);    //    131,072
    unsigned short* wt_out = (unsigned short*)(w8 + 50991104);    //    131,072
    unsigned short* wt_oa  = (unsigned short*)(w8 + 51122176);    //     65,536
    float*          b_oa   = (float*)(w8 + 51187712);             //        512
    __half*         kth    = (__half*)(w8 + 51188224);            //     25,088
    unsigned short* out_attn = q_act;  // alias: q_act dead after oa GEMM

    // merged weight prep + border zero
    prep_kernel<<<1849, 256, 0, stream>>>(
        dwk, Wval, Wout, Woff, boff, Wattn, battn,
        kth, wt_val, wt_out, wt_oa, b_oa, v_pad);

    // conv + LN + GELU -> bf16 q_act (fp32 query in, fp16x2 math, DPP LN)
    {
        dim3 grid(WW / 8, HH, NB);
        conv_ln_gelu_kernel<<<grid, 128, 0, stream>>>(
            query, kth, dwb, lnw, lnb, q_act);
    }

    // value GEMM (padded bf16 layout) + oa GEMM, one launch
    {
        dim3 grid(M / 128, 3);
        gemm_val_oa<<<grid, 256, 0, stream>>>(
            q_act, wt_val, bval, v_pad, wt_oa, b_oa, oa);
    }

    // sampling + weighted sum -> bf16  (8 rows/block, 16B gathers)
    sampler_kernel<<<M / 8, 256, 0, stream>>>(rp, oa, v_pad, out_attn);

    // output GEMM -> d_out fp32
    {
        dim3 grid(M / 128, 2);
        gemm_mfma_row<<<grid, 256, 0, stream>>>(out_attn, wt_out, bout, out, 256);
    }
}

// Round 14
// 86.628 us; speedup vs baseline: 1.2021x; 1.2021x over previous
//
#include <hip/hip_runtime.h>
#include <hip/hip_bf16.h>
#include <hip/hip_fp16.h>
#include <math.h>

// Problem constants
#define NB   2
#define CC   256
#define HH   128
#define WW   128
#define HPP  130
#define WPP  130
#define LQ   16384   // HH*WW

typedef __attribute__((ext_vector_type(8))) short short8;
typedef __attribute__((ext_vector_type(8))) unsigned short u16x8;
typedef __attribute__((ext_vector_type(4))) float f32x4;
typedef __attribute__((ext_vector_type(4))) unsigned int u32x4;

static __device__ __forceinline__ unsigned short f2bf(float f) {
    __hip_bfloat16 h = __float2bfloat16(f);
    return __builtin_bit_cast(unsigned short, h);
}
static __device__ __forceinline__ float bf2f(unsigned short u) {
    unsigned int x = ((unsigned int)u) << 16;
    return __builtin_bit_cast(float, x);
}

// branch-free tanh-form GELU: x * sigmoid(1.5957691*(x + 0.044715 x^3))
static __device__ __forceinline__ float gelu_fast(float x) {
    float u = x * x;
    float t = x * fmaf(0.044715f, u, 1.0f);
    float e = __builtin_amdgcn_exp2f(t * 2.3022083f);
    float r = __builtin_amdgcn_rcpf(e + 1.0f);
    return x - x * r;
}

// -------------------------------------------------------------------------
// Kernel A: merged weight prep + v_pad border zero + query fp32->fp16.
// blocks 0..48      : kth[k][c] = half(dwk[c][k])
// blocks 49..304    : wt_val
// blocks 305..560   : wt_out
// blocks 561..816   : wt_oa + b_oa
// blocks 817..1848  : v_pad border zero (1032 positions)
// blocks 1849..5944 : query f32 -> f16 (8,388,608 elements, 2048/block)
// -------------------------------------------------------------------------
__global__ __launch_bounds__(256) void prep_kernel(
    const float* __restrict__ dwk,
    const float* __restrict__ Wval,
    const float* __restrict__ Wout,
    const float* __restrict__ Woff, const float* __restrict__ boff,
    const float* __restrict__ Wattn, const float* __restrict__ battn,
    const float* __restrict__ query,
    __half* __restrict__ kth,
    unsigned short* __restrict__ wt_val,
    unsigned short* __restrict__ wt_out,
    unsigned short* __restrict__ wt_oa,
    float* __restrict__ b_oa,
    unsigned short* __restrict__ vpad,
    __half* __restrict__ qh)
{
    int b = blockIdx.x;
    int t = threadIdx.x;
    if (b < 49) {
        kth[b * CC + t] = __float2half(dwk[t * 49 + b]);
    } else if (b < 305) {
        int k = b - 49;
        wt_val[(size_t)t * 256 + k] = f2bf(Wval[(size_t)k * 256 + t]);
    } else if (b < 561) {
        int k = b - 305;
        wt_out[(size_t)t * 256 + k] = f2bf(Wout[(size_t)k * 256 + t]);
    } else if (b < 817) {
        int k = b - 561;
        if (t < 128) {
            float v = 0.f, bb = 0.f;
            if (t < 64)      { v = Woff[(size_t)k * 64 + t];        bb = boff[t]; }
            else if (t < 96) { v = Wattn[(size_t)k * 32 + (t - 64)]; bb = battn[t - 64]; }
            wt_oa[(size_t)t * 256 + k] = f2bf(v);
            if (k == 0) b_oa[t] = bb;
        }
    } else if (b < 1849) {
        int bb = b - 817;
        int n = (bb >= 516) ? 1 : 0;
        int i = bb - n * 516;
        int y, x;
        if (i < 130)      { y = 0;           x = i; }
        else if (i < 260) { y = 129;         x = i - 130; }
        else if (i < 388) { y = i - 260 + 1; x = 0; }
        else              { y = i - 388 + 1; x = 129; }
        vpad[(((size_t)n * HPP + y) * WPP + x) * CC + t] = 0;
    } else {
        size_t idx0 = (size_t)(b - 1849) * 2048 + (size_t)t * 8;
        const float4* src = reinterpret_cast<const float4*>(query + idx0);
        float4 f0 = src[0];
        float4 f1 = src[1];
        __half2 h0 = __floats2half2_rn(f0.x, f0.y);
        __half2 h1 = __floats2half2_rn(f0.z, f0.w);
        __half2 h2 = __floats2half2_rn(f1.x, f1.y);
        __half2 h3 = __floats2half2_rn(f1.z, f1.w);
        u32x4 o;
        o.x = __builtin_bit_cast(unsigned int, h0);
        o.y = __builtin_bit_cast(unsigned int, h1);
        o.z = __builtin_bit_cast(unsigned int, h2);
        o.w = __builtin_bit_cast(unsigned int, h3);
        *reinterpret_cast<u32x4*>(qh + idx0) = o;
    }
}

// -------------------------------------------------------------------------
// Kernel 1: fused depthwise 7x7 conv (fp16x2 packed) + bias + channel-LN
// + GELU -> bf16.  Lane = 4 channels (2 x half2); ONE WAVE spans all 256
// channels -> LN is pure intra-wave shuffles (no LDS combine, no barrier).
// Wave = 8 w-positions; block = 4 waves = 32 w-positions.
// -------------------------------------------------------------------------
__global__ __launch_bounds__(256) void conv_ln_gelu_kernel(
    const __half* __restrict__ qh,    // (N, LQ, C) fp16
    const __half* __restrict__ kth,   // (49, C) fp16
    const float* __restrict__ kbias,
    const float* __restrict__ lnw,
    const float* __restrict__ lnb,
    unsigned short* __restrict__ qact) // (N, LQ, C) bf16
{
    int lane = threadIdx.x & 63;
    int wv   = threadIdx.x >> 6;      // 0..3
    int w0   = blockIdx.x * 32 + wv * 8;
    int h    = blockIdx.y;
    int n    = blockIdx.z;
    int c2   = lane * 2;              // half2-unit base (channels 4*lane..4*lane+3)

    const __half2* qn  = reinterpret_cast<const __half2*>(qh) + (size_t)(n * LQ) * 128 + c2;
    const __half2* ktc = reinterpret_cast<const __half2*>(kth) + c2;

    __half2 acc0[8], acc1[8];
    #pragma unroll
    for (int i = 0; i < 8; ++i) {
        acc0[i] = __half2(0.f, 0.f);
        acc1[i] = __half2(0.f, 0.f);
    }

    if (w0 >= 8 && w0 <= 112 && h >= 3 && h <= 124) {
        // -------- interior: no bounds checks --------
        #pragma unroll
        for (int ky = 0; ky < 7; ++ky) {
            const __half2* qrow = qn + ((size_t)(h + ky - 3) * WW + (w0 - 3)) * 128;
            __half2 wta[7], wtb[7];
            #pragma unroll
            for (int kx = 0; kx < 7; ++kx) {
                wta[kx] = ktc[(ky * 7 + kx) * 128];
                wtb[kx] = ktc[(ky * 7 + kx) * 128 + 1];
            }
            __half2 ina[14], inb[14];
            #pragma unroll
            for (int j = 0; j < 14; ++j) {
                ina[j] = qrow[(size_t)j * 128];
                inb[j] = qrow[(size_t)j * 128 + 1];
            }
            #pragma unroll
            for (int i = 0; i < 8; ++i)
                #pragma unroll
                for (int kx = 0; kx < 7; ++kx) {
                    acc0[i] = __hfma2(ina[i + kx], wta[kx], acc0[i]);
                    acc1[i] = __hfma2(inb[i + kx], wtb[kx], acc1[i]);
                }
        }
    } else {
        // -------- border: zero-fill checked loads --------
        #pragma unroll
        for (int ky = 0; ky < 7; ++ky) {
            int iy = h + ky - 3;
            if (iy < 0 || iy >= HH) continue;
            const __half2* qrow = qn + (size_t)iy * WW * 128;
            __half2 wta[7], wtb[7];
            #pragma unroll
            for (int kx = 0; kx < 7; ++kx) {
                wta[kx] = ktc[(ky * 7 + kx) * 128];
                wtb[kx] = ktc[(ky * 7 + kx) * 128 + 1];
            }
            __half2 ina[14], inb[14];
            #pragma unroll
            for (int j = 0; j < 14; ++j) {
                int ix = w0 - 3 + j;
                bool ok = (ix >= 0 && ix < WW);
                ina[j] = ok ? qrow[(size_t)ix * 128]     : __half2(0.f, 0.f);
                inb[j] = ok ? qrow[(size_t)ix * 128 + 1] : __half2(0.f, 0.f);
            }
            #pragma unroll
            for (int i = 0; i < 8; ++i)
                #pragma unroll
                for (int kx = 0; kx < 7; ++kx) {
                    acc0[i] = __hfma2(ina[i + kx], wta[kx], acc0[i]);
                    acc1[i] = __hfma2(inb[i + kx], wtb[kx], acc1[i]);
                }
        }
    }

    // unpack to fp32 + conv bias (4 channels per lane)
    int c4 = lane * 4;
    float kb0 = kbias[c4], kb1 = kbias[c4 + 1], kb2 = kbias[c4 + 2], kb3 = kbias[c4 + 3];
    float a[8][4];
    #pragma unroll
    for (int i = 0; i < 8; ++i) {
        a[i][0] = __low2float(acc0[i])  + kb0;
        a[i][1] = __high2float(acc0[i]) + kb1;
        a[i][2] = __low2float(acc1[i])  + kb2;
        a[i][3] = __high2float(acc1[i]) + kb3;
    }

    float lw0 = lnw[c4], lw1 = lnw[c4 + 1], lw2 = lnw[c4 + 2], lw3 = lnw[c4 + 3];
    float lb0 = lnb[c4], lb1 = lnb[c4 + 1], lb2 = lnb[c4 + 2], lb3 = lnb[c4 + 3];
    unsigned short* qo = qact + (((size_t)n * LQ) + (size_t)h * WW + w0) * CC + c4;

    // LayerNorm per position: intra-wave butterfly (all 256 ch in one wave)
    #pragma unroll
    for (int i = 0; i < 8; ++i) {
        float s  = a[i][0] + a[i][1] + a[i][2] + a[i][3];
        float sq = a[i][0]*a[i][0] + a[i][1]*a[i][1]
                 + a[i][2]*a[i][2] + a[i][3]*a[i][3];
        #pragma unroll
        for (int m = 1; m < 64; m <<= 1) {
            s  += __shfl_xor(s,  m);
            sq += __shfl_xor(sq, m);
        }
        float mu  = s * (1.0f / 256.0f);
        float var = sq * (1.0f / 256.0f) - mu * mu;
        float inv = rsqrtf(var + 1e-5f);
        ushort4 o;
        o.x = f2bf(gelu_fast((a[i][0] - mu) * inv * lw0 + lb0));
        o.y = f2bf(gelu_fast((a[i][1] - mu) * inv * lw1 + lb1));
        o.z = f2bf(gelu_fast((a[i][2] - mu) * inv * lw2 + lb2));
        o.w = f2bf(gelu_fast((a[i][3] - mu) * inv * lw3 + lb3));
        *reinterpret_cast<ushort4*>(qo + (size_t)i * CC) = o;
    }
}

// -------------------------------------------------------------------------
// Kernel 2a: merged value + oa GEMM (bf16 MFMA), grid.y: 0,1=val  2=oa
// -------------------------------------------------------------------------
__global__ __launch_bounds__(256) void gemm_val_oa(
    const unsigned short* __restrict__ A,
    const unsigned short* __restrict__ Bv, const float* __restrict__ bv_,
    unsigned short* __restrict__ Cv,
    const unsigned short* __restrict__ Bo, const float* __restrict__ bo_,
    float* __restrict__ Co)
{
    __shared__ unsigned short Al[128][72];
    __shared__ unsigned short Bl[128][72];

    bool oam = (blockIdx.y == 2);
    const unsigned short* Bt = oam ? Bo : Bv;
    const float* bias = oam ? bo_ : bv_;
    int bn = oam ? 0 : blockIdx.y * 128;

    int t    = threadIdx.x;
    int bm   = blockIdx.x * 128;
    int wid  = t >> 6;
    int lane = t & 63;
    int wr   = wid >> 1;
    int wc   = wid & 1;
    int lr   = lane & 15;
    int lg   = lane >> 4;

    int srow = t >> 1;
    int sseg = (t & 1) << 5;

    const unsigned short* gA = A + (size_t)(bm + srow) * 256 + sseg;
    const unsigned short* gB = Bt + (size_t)(bn + srow) * 256 + sseg;
    unsigned short* lA = &Al[srow][sseg];
    unsigned short* lB = &Bl[srow][sseg];

    f32x4 acc[4][4] = {};

    for (int kt = 0; kt < 4; ++kt) {
        const unsigned short* ga = gA + kt * 64;
        const unsigned short* gb = gB + kt * 64;
        u32x4 a0 = *(const u32x4*)(ga);
        u32x4 a1 = *(const u32x4*)(ga + 8);
        u32x4 a2 = *(const u32x4*)(ga + 16);
        u32x4 a3 = *(const u32x4*)(ga + 24);
        u32x4 b0 = *(const u32x4*)(gb);
        u32x4 b1 = *(const u32x4*)(gb + 8);
        u32x4 b2 = *(const u32x4*)(gb + 16);
        u32x4 b3 = *(const u32x4*)(gb + 24);
        *(u32x4*)(lA)      = a0;
        *(u32x4*)(lA + 8)  = a1;
        *(u32x4*)(lA + 16) = a2;
        *(u32x4*)(lA + 24) = a3;
        *(u32x4*)(lB)      = b0;
        *(u32x4*)(lB + 8)  = b1;
        *(u32x4*)(lB + 16) = b2;
        *(u32x4*)(lB + 24) = b3;
        __syncthreads();

        #pragma unroll
        for (int kk = 0; kk < 2; ++kk) {
            short8 af[4], bfr[4];
            #pragma unroll
            for (int m = 0; m < 4; ++m)
                af[m] = *(const short8*)(&Al[wr * 64 + m * 16 + lr][kk * 32 + lg * 8]);
            #pragma unroll
            for (int nn = 0; nn < 4; ++nn)
                bfr[nn] = *(const short8*)(&Bl[wc * 64 + nn * 16 + lr][kk * 32 + lg * 8]);
            #pragma unroll
            for (int m = 0; m < 4; ++m)
                #pragma unroll
                for (int nn = 0; nn < 4; ++nn)
                    acc[m][nn] = __builtin_amdgcn_mfma_f32_16x16x32_bf16(
                        af[m], bfr[nn], acc[m][nn], 0, 0, 0);
        }
        __syncthreads();
    }

    float bvv[4];
    #pragma unroll
    for (int nn = 0; nn < 4; ++nn) bvv[nn] = bias[bn + wc * 64 + nn * 16 + lr];

    #pragma unroll
    for (int m = 0; m < 4; ++m) {
        #pragma unroll
        for (int j = 0; j < 4; ++j) {
            int row = bm + wr * 64 + m * 16 + lg * 4 + j;
            if (oam) {
                size_t rbase = (size_t)row * 128;
                #pragma unroll
                for (int nn = 0; nn < 4; ++nn) {
                    int col = wc * 64 + nn * 16 + lr;
                    Co[rbase + col] = acc[m][nn][j] + bvv[nn];
                }
            } else {
                int nb = row >> 14;
                int hw = row & 16383;
                int hh = hw >> 7;
                int ww = hw & 127;
                size_t rbase = (((size_t)nb * HPP + (hh + 1)) * WPP + (ww + 1)) * CC;
                #pragma unroll
                for (int nn = 0; nn < 4; ++nn) {
                    int col = bn + wc * 64 + nn * 16 + lr;
                    Cv[rbase + col] = f2bf(acc[m][nn][j] + bvv[nn]);
                }
            }
        }
    }
}

// -------------------------------------------------------------------------
// Kernel 2b: bf16 MFMA GEMM, row-major fp32 store (output GEMM)
// -------------------------------------------------------------------------
__global__ __launch_bounds__(256) void gemm_mfma_row(
    const unsigned short* __restrict__ A,
    const unsigned short* __restrict__ Bt,
    const float* __restrict__ bias,
    float* __restrict__ C,
    int Nn)
{
    __shared__ unsigned short Al[128][72];
    __shared__ unsigned short Bl[128][72];

    int t    = threadIdx.x;
    int bm   = blockIdx.x * 128;
    int bn   = blockIdx.y * 128;
    int wid  = t >> 6;
    int lane = t & 63;
    int wr   = wid >> 1;
    int wc   = wid & 1;
    int lr   = lane & 15;
    int lg   = lane >> 4;

    int srow = t >> 1;
    int sseg = (t & 1) << 5;

    const unsigned short* gA = A + (size_t)(bm + srow) * 256 + sseg;
    const unsigned short* gB = Bt + (size_t)(bn + srow) * 256 + sseg;
    unsigned short* lA = &Al[srow][sseg];
    unsigned short* lB = &Bl[srow][sseg];

    f32x4 acc[4][4] = {};

    for (int kt = 0; kt < 4; ++kt) {
        const unsigned short* ga = gA + kt * 64;
        const unsigned short* gb = gB + kt * 64;
        u32x4 a0 = *(const u32x4*)(ga);
        u32x4 a1 = *(const u32x4*)(ga + 8);
        u32x4 a2 = *(const u32x4*)(ga + 16);
        u32x4 a3 = *(const u32x4*)(ga + 24);
        u32x4 b0 = *(const u32x4*)(gb);
        u32x4 b1 = *(const u32x4*)(gb + 8);
        u32x4 b2 = *(const u32x4*)(gb + 16);
        u32x4 b3 = *(const u32x4*)(gb + 24);
        *(u32x4*)(lA)      = a0;
        *(u32x4*)(lA + 8)  = a1;
        *(u32x4*)(lA + 16) = a2;
        *(u32x4*)(lA + 24) = a3;
        *(u32x4*)(lB)      = b0;
        *(u32x4*)(lB + 8)  = b1;
        *(u32x4*)(lB + 16) = b2;
        *(u32x4*)(lB + 24) = b3;
        __syncthreads();

        #pragma unroll
        for (int kk = 0; kk < 2; ++kk) {
            short8 af[4], bfr[4];
            #pragma unroll
            for (int m = 0; m < 4; ++m)
                af[m] = *(const short8*)(&Al[wr * 64 + m * 16 + lr][kk * 32 + lg * 8]);
            #pragma unroll
            for (int nn = 0; nn < 4; ++nn)
                bfr[nn] = *(const short8*)(&Bl[wc * 64 + nn * 16 + lr][kk * 32 + lg * 8]);
            #pragma unroll
            for (int m = 0; m < 4; ++m)
                #pragma unroll
                for (int nn = 0; nn < 4; ++nn)
                    acc[m][nn] = __builtin_amdgcn_mfma_f32_16x16x32_bf16(
                        af[m], bfr[nn], acc[m][nn], 0, 0, 0);
        }
        __syncthreads();
    }

    float bvv[4];
    #pragma unroll
    for (int nn = 0; nn < 4; ++nn) bvv[nn] = bias[bn + wc * 64 + nn * 16 + lr];

    #pragma unroll
    for (int m = 0; m < 4; ++m) {
        #pragma unroll
        for (int j = 0; j < 4; ++j) {
            int row = bm + wr * 64 + m * 16 + lg * 4 + j;
            size_t rbase = (size_t)row * Nn;
            #pragma unroll
            for (int nn = 0; nn < 4; ++nn) {
                int col = bn + wc * 64 + nn * 16 + lr;
                C[rbase + col] = acc[m][nn][j] + bvv[nn];
            }
        }
    }
}

// -------------------------------------------------------------------------
// Kernel 3: deformable bilinear sampling + attention-weighted sum
// 8 rows/block; phase 1: 256 threads = (8 rows x 8 heads x 4 points);
// phase 2: thread = 8 channels (ushort8 16B gathers), 32 threads/row.
// -------------------------------------------------------------------------
__global__ __launch_bounds__(256) void sampler_kernel(
    const float* __restrict__ rp,            // (N, LQ, 1, 2)
    const float* __restrict__ oa,            // (N*LQ, 128)
    const unsigned short* __restrict__ vpad, // (N, HP, WP, C) bf16
    unsigned short* __restrict__ outb)       // (N*LQ, C) bf16
{
    __shared__ int4   sIdx[8][4][8];
    __shared__ float4 sW[8][4][8];

    int tid  = threadIdx.x;
    int row0 = blockIdx.x * 8;

    {
        int rl   = tid >> 5;
        int hp   = tid & 31;
        int head = hp >> 2;
        int p    = hp & 3;
        int row  = row0 + rl;

        float ref0 = rp[(size_t)row * 2 + 0];
        float ref1 = rp[(size_t)row * 2 + 1];
        float o0 = oa[(size_t)row * 128 + head * 8 + p * 2 + 0];
        float o1 = oa[(size_t)row * 128 + head * 8 + p * 2 + 1];
        float al = oa[(size_t)row * 128 + 64 + head * 4 + p];
        float a  = 1.0f / (1.0f + __builtin_amdgcn_exp2f(-al * 1.4426950409f));

        float gy = (float)(p >> 1);
        float gx = (float)(p & 1);
        float x = ref0 * WPP + gy + o0 - 0.5f;
        float y = ref1 * HPP + gx + o1 - 0.5f;

        float x0f = floorf(x), y0f = floorf(y);
        int   x0  = (int)x0f,  y0  = (int)y0f;
        float wx1 = x - x0f, wx0 = 1.f - wx1;
        float wy1 = y - y0f, wy0 = 1.f - wy1;
        int x1 = x0 + 1, y1 = y0 + 1;

        bool vx0 = (x0 >= 0) & (x0 < WPP);
        bool vx1 = (x1 >= 0) & (x1 < WPP);
        bool vy0 = (y0 >= 0) & (y0 < HPP);
        bool vy1 = (y1 >= 0) & (y1 < HPP);
        int cx0 = min(max(x0, 0), WPP - 1);
        int cx1 = min(max(x1, 0), WPP - 1);
        int cy0 = min(max(y0, 0), HPP - 1);
        int cy1 = min(max(y1, 0), HPP - 1);

        int4 id;
        id.x = cy0 * WPP + cx0;
        id.y = cy0 * WPP + cx1;
        id.z = cy1 * WPP + cx0;
        id.w = cy1 * WPP + cx1;
        float4 w;
        w.x = (vx0 && vy0) ? a * wx0 * wy0 : 0.f;
        w.y = (vx1 && vy0) ? a * wx1 * wy0 : 0.f;
        w.z = (vx0 && vy1) ? a * wx0 * wy1 : 0.f;
        w.w = (vx1 && vy1) ? a * wx1 * wy1 : 0.f;

        sIdx[rl][p][head] = id;
        sW[rl][p][head]   = w;
    }
    __syncthreads();

    int rl   = tid >> 5;
    int c0   = (tid & 31) * 8;
    int head = (tid & 31) >> 2;
    int row  = row0 + rl;
    int n    = row >> 14;
    const unsigned short* vbase = vpad + (size_t)n * HPP * WPP * CC + c0;

    float acc[8] = {};
    #pragma unroll
    for (int p = 0; p < 4; ++p) {
        int4   id = sIdx[rl][p][head];
        float4 w  = sW[rl][p][head];
        u16x8 g0 = *reinterpret_cast<const u16x8*>(vbase + (size_t)id.x * CC);
        u16x8 g1 = *reinterpret_cast<const u16x8*>(vbase + (size_t)id.y * CC);
        u16x8 g2 = *reinterpret_cast<const u16x8*>(vbase + (size_t)id.z * CC);
        u16x8 g3 = *reinterpret_cast<const u16x8*>(vbase + (size_t)id.w * CC);
        #pragma unroll
        for (int j = 0; j < 8; ++j) {
            acc[j] += w.x * bf2f(g0[j]) + w.y * bf2f(g1[j])
                    + w.z * bf2f(g2[j]) + w.w * bf2f(g3[j]);
        }
    }
    u16x8 o;
    #pragma unroll
    for (int j = 0; j < 8; ++j) o[j] = f2bf(acc[j]);
    *reinterpret_cast<u16x8*>(&outb[(size_t)row * CC + c0]) = o;
}

// -------------------------------------------------------------------------
extern "C" void kernel_launch(void* const* d_in, const int* in_sizes, int n_in,
                              void* d_out, int out_size, void* d_ws, size_t ws_size,
                              hipStream_t stream)
{
    const float* query = (const float*)d_in[0];
    const float* rp    = (const float*)d_in[1];
    const float* dwk   = (const float*)d_in[4];
    const float* dwb   = (const float*)d_in[5];
    const float* lnw   = (const float*)d_in[6];
    const float* lnb   = (const float*)d_in[7];
    const float* Woff  = (const float*)d_in[8];
    const float* boff  = (const float*)d_in[9];
    const float* Wattn = (const float*)d_in[10];
    const float* battn = (const float*)d_in[11];
    const float* Wval  = (const float*)d_in[12];
    const float* bval  = (const float*)d_in[13];
    const float* Wout  = (const float*)d_in[14];
    const float* bout  = (const float*)d_in[15];
    float* out = (float*)d_out;

    const int M = NB * LQ;  // 32768

    // workspace layout (bytes)
    uint8_t* w8 = (uint8_t*)d_ws;
    unsigned short* q_act  = (unsigned short*)w8;                 // 16,777,216
    unsigned short* v_pad  = (unsigned short*)(w8 + 16777216);    // 17,305,600 (bf16)
    float*          oa     = (float*)(w8 + 34082816);             // 16,777,216
    __half*         qh     = (__half*)(w8 + 50860032);            // 16,777,216 (fp16)
    unsigned short* wt_val = (unsigned short*)(w8 + 67637248);    //    131,072
    unsigned short* wt_out = (unsigned short*)(w8 + 67768320);    //    131,072
    unsigned short* wt_oa  = (unsigned short*)(w8 + 67899392);    //     65,536
    float*          b_oa   = (float*)(w8 + 67964928);             //        512
    __half*         kth    = (__half*)(w8 + 67965440);            //     25,088
    unsigned short* out_attn = q_act;  // alias: q_act dead after oa GEMM

    // merged weight prep + border zero + query f32->f16
    prep_kernel<<<5945, 256, 0, stream>>>(
        dwk, Wval, Wout, Woff, boff, Wattn, battn, query,
        kth, wt_val, wt_out, wt_oa, b_oa, v_pad, qh);

    // conv + LN + GELU -> bf16 q_act  (4 ch/lane, 1 wave = 256 ch)
    {
        dim3 grid(WW / 32, HH, NB);
        conv_ln_gelu_kernel<<<grid, 256, 0, stream>>>(
            qh, kth, dwb, lnw, lnb, q_act);
    }

    // value GEMM (padded bf16 layout) + oa GEMM, one launch
    {
        dim3 grid(M / 128, 3);
        gemm_val_oa<<<grid, 256, 0, stream>>>(
            q_act, wt_val, bval, v_pad, wt_oa, b_oa, oa);
    }

    // sampling + weighted sum -> bf16  (8 rows/block, 16B gathers)
    sampler_kernel<<<M / 8, 256, 0, stream>>>(rp, oa, v_pad, out_attn);

    // output GEMM -> d_out fp32
    {
        dim3 grid(M / 128, 2);
        gemm_mfma_row<<<grid, 256, 0, stream>>>(out_attn, wt_out, bout, out, 256);
    }
}

// Round 15
// 84.459 us; speedup vs baseline: 1.2330x; 1.0257x over previous
//
#include <hip/hip_runtime.h>
#include <hip/hip_bf16.h>
#include <hip/hip_fp16.h>
#include <math.h>

// Problem constants
#define NB   2
#define CC   256
#define HH   128
#define WW   128
#define HPP  130
#define WPP  130
#define LQ   16384   // HH*WW

typedef __attribute__((ext_vector_type(8))) short short8;
typedef __attribute__((ext_vector_type(8))) unsigned short u16x8;
typedef __attribute__((ext_vector_type(4))) float f32x4;
typedef __attribute__((ext_vector_type(4))) unsigned int u32x4;

static __device__ __forceinline__ unsigned short f2bf(float f) {
    __hip_bfloat16 h = __float2bfloat16(f);
    return __builtin_bit_cast(unsigned short, h);
}
static __device__ __forceinline__ float bf2f(unsigned short u) {
    unsigned int x = ((unsigned int)u) << 16;
    return __builtin_bit_cast(float, x);
}

// branch-free tanh-form GELU: x * sigmoid(1.5957691*(x + 0.044715 x^3))
static __device__ __forceinline__ float gelu_fast(float x) {
    float u = x * x;
    float t = x * fmaf(0.044715f, u, 1.0f);
    float e = __builtin_amdgcn_exp2f(t * 2.3022083f);
    float r = __builtin_amdgcn_rcpf(e + 1.0f);
    return x - x * r;
}

// ---- DPP wave-64 sum reduction (VALU pipe, no LDS) ----------------------
// Validated on HW in R13 (passed, absmax 0.0176). Lane 63 holds the sum.
template <int CTRL, int RMASK, int BMASK>
static __device__ __forceinline__ float dpp_add(float x) {
    int s = __builtin_bit_cast(int, x);
    int d = __builtin_amdgcn_update_dpp(0, s, CTRL, RMASK, BMASK, true);
    return x + __builtin_bit_cast(float, d);
}
static __device__ __forceinline__ float wave_sum_lane63(float x) {
    x = dpp_add<0x111, 0xf, 0xf>(x);   // row_shr:1
    x = dpp_add<0x112, 0xf, 0xf>(x);   // row_shr:2
    x = dpp_add<0x114, 0xf, 0xe>(x);   // row_shr:4  bank_mask 0xe
    x = dpp_add<0x118, 0xf, 0xc>(x);   // row_shr:8  bank_mask 0xc
    x = dpp_add<0x142, 0xa, 0xf>(x);   // row_bcast:15 row_mask 0xa
    x = dpp_add<0x143, 0xc, 0xf>(x);   // row_bcast:31 row_mask 0xc
    return x;                          // valid in lane 63
}

// -------------------------------------------------------------------------
// Kernel A: merged weight prep + v_pad border zero + query fp32->fp16.
// -------------------------------------------------------------------------
__global__ __launch_bounds__(256) void prep_kernel(
    const float* __restrict__ dwk,
    const float* __restrict__ Wval,
    const float* __restrict__ Wout,
    const float* __restrict__ Woff, const float* __restrict__ boff,
    const float* __restrict__ Wattn, const float* __restrict__ battn,
    const float* __restrict__ query,
    __half* __restrict__ kth,
    unsigned short* __restrict__ wt_val,
    unsigned short* __restrict__ wt_out,
    unsigned short* __restrict__ wt_oa,
    float* __restrict__ b_oa,
    unsigned short* __restrict__ vpad,
    __half* __restrict__ qh)
{
    int b = blockIdx.x;
    int t = threadIdx.x;
    if (b < 49) {
        kth[b * CC + t] = __float2half(dwk[t * 49 + b]);
    } else if (b < 305) {
        int k = b - 49;
        wt_val[(size_t)t * 256 + k] = f2bf(Wval[(size_t)k * 256 + t]);
    } else if (b < 561) {
        int k = b - 305;
        wt_out[(size_t)t * 256 + k] = f2bf(Wout[(size_t)k * 256 + t]);
    } else if (b < 817) {
        int k = b - 561;
        if (t < 128) {
            float v = 0.f, bb = 0.f;
            if (t < 64)      { v = Woff[(size_t)k * 64 + t];        bb = boff[t]; }
            else if (t < 96) { v = Wattn[(size_t)k * 32 + (t - 64)]; bb = battn[t - 64]; }
            wt_oa[(size_t)t * 256 + k] = f2bf(v);
            if (k == 0) b_oa[t] = bb;
        }
    } else if (b < 1849) {
        int bb = b - 817;
        int n = (bb >= 516) ? 1 : 0;
        int i = bb - n * 516;
        int y, x;
        if (i < 130)      { y = 0;           x = i; }
        else if (i < 260) { y = 129;         x = i - 130; }
        else if (i < 388) { y = i - 260 + 1; x = 0; }
        else              { y = i - 388 + 1; x = 129; }
        vpad[(((size_t)n * HPP + y) * WPP + x) * CC + t] = 0;
    } else {
        size_t idx0 = (size_t)(b - 1849) * 2048 + (size_t)t * 8;
        const float4* src = reinterpret_cast<const float4*>(query + idx0);
        float4 f0 = src[0];
        float4 f1 = src[1];
        __half2 h0 = __floats2half2_rn(f0.x, f0.y);
        __half2 h1 = __floats2half2_rn(f0.z, f0.w);
        __half2 h2 = __floats2half2_rn(f1.x, f1.y);
        __half2 h3 = __floats2half2_rn(f1.z, f1.w);
        u32x4 o;
        o.x = __builtin_bit_cast(unsigned int, h0);
        o.y = __builtin_bit_cast(unsigned int, h1);
        o.z = __builtin_bit_cast(unsigned int, h2);
        o.w = __builtin_bit_cast(unsigned int, h3);
        *reinterpret_cast<u32x4*>(qh + idx0) = o;
    }
}

// -------------------------------------------------------------------------
// Kernel 1: fused depthwise 7x7 conv (fp16x2 packed) + bias + channel-LN
// + GELU -> bf16.  R10 known-good structure: block = 128 threads (2 waves),
// thread = channel PAIR, 8 w-positions.  ONLY change vs R10: LN reduce on
// the VALU via DPP instead of __shfl_xor (DS pipe).
// -------------------------------------------------------------------------
__global__ __launch_bounds__(128) void conv_ln_gelu_kernel(
    const __half* __restrict__ qh,    // (N, LQ, C) fp16
    const __half* __restrict__ kth,   // (49, C) fp16
    const float* __restrict__ kbias,
    const float* __restrict__ lnw,
    const float* __restrict__ lnb,
    unsigned short* __restrict__ qact) // (N, LQ, C) bf16
{
    int t  = threadIdx.x;             // 0..127 -> channels 2t, 2t+1
    int w0 = blockIdx.x * 8;
    int h  = blockIdx.y;
    int n  = blockIdx.z;

    const __half2* qn  = reinterpret_cast<const __half2*>(qh + (size_t)n * LQ * CC) + t;
    const __half2* ktc = reinterpret_cast<const __half2*>(kth) + t;

    __half2 acc[8];
    #pragma unroll
    for (int i = 0; i < 8; ++i) acc[i] = __half2(0.f, 0.f);

    if (w0 >= 8 && w0 <= 112 && h >= 3 && h <= 124) {
        #pragma unroll
        for (int ky = 0; ky < 7; ++ky) {
            const __half2* qrow = qn + ((size_t)(h + ky - 3) * WW + (w0 - 3)) * 128;
            __half2 wt[7];
            #pragma unroll
            for (int kx = 0; kx < 7; ++kx)
                wt[kx] = ktc[(ky * 7 + kx) * 128];
            __half2 in[14];
            #pragma unroll
            for (int j = 0; j < 14; ++j)
                in[j] = qrow[(size_t)j * 128];
            #pragma unroll
            for (int i = 0; i < 8; ++i)
                #pragma unroll
                for (int kx = 0; kx < 7; ++kx)
                    acc[i] = __hfma2(in[i + kx], wt[kx], acc[i]);
        }
    } else {
        #pragma unroll
        for (int ky = 0; ky < 7; ++ky) {
            int iy = h + ky - 3;
            if (iy < 0 || iy >= HH) continue;
            const __half2* qrow = qn + (size_t)iy * WW * 128;
            __half2 wt[7];
            #pragma unroll
            for (int kx = 0; kx < 7; ++kx)
                wt[kx] = ktc[(ky * 7 + kx) * 128];
            __half2 in[14];
            #pragma unroll
            for (int j = 0; j < 14; ++j) {
                int ix = w0 - 3 + j;
                in[j] = (ix >= 0 && ix < WW) ? qrow[(size_t)ix * 128]
                                             : __half2(0.f, 0.f);
            }
            #pragma unroll
            for (int i = 0; i < 8; ++i)
                #pragma unroll
                for (int kx = 0; kx < 7; ++kx)
                    acc[i] = __hfma2(in[i + kx], wt[kx], acc[i]);
        }
    }

    float b0 = kbias[2 * t];
    float b1 = kbias[2 * t + 1];
    float a0[8], a1[8];
    #pragma unroll
    for (int i = 0; i < 8; ++i) {
        a0[i] = __low2float(acc[i])  + b0;
        a1[i] = __high2float(acc[i]) + b1;
    }

    // LayerNorm stats: DPP wave-reduce (VALU pipe), 2-wave combine via LDS
    __shared__ float lsum[8][2];
    __shared__ float lsq[8][2];
    int lane = t & 63;
    int wv   = t >> 6;

    #pragma unroll
    for (int i = 0; i < 8; ++i) {
        float s  = wave_sum_lane63(a0[i] + a1[i]);
        float sq = wave_sum_lane63(a0[i] * a0[i] + a1[i] * a1[i]);
        if (lane == 63) { lsum[i][wv] = s; lsq[i][wv] = sq; }
    }
    __syncthreads();

    float lw0 = lnw[2 * t], lw1 = lnw[2 * t + 1];
    float lb0 = lnb[2 * t], lb1 = lnb[2 * t + 1];
    unsigned short* qo = qact + (((size_t)n * LQ) + (size_t)h * WW + w0) * CC + 2 * t;

    #pragma unroll
    for (int i = 0; i < 8; ++i) {
        float s   = lsum[i][0] + lsum[i][1];
        float sq  = lsq[i][0]  + lsq[i][1];
        float mu  = s * (1.0f / 256.0f);
        float var = sq * (1.0f / 256.0f) - mu * mu;
        float inv = rsqrtf(var + 1e-5f);
        float g0 = gelu_fast((a0[i] - mu) * inv * lw0 + lb0);
        float g1 = gelu_fast((a1[i] - mu) * inv * lw1 + lb1);
        ushort2 o;
        o.x = f2bf(g0);
        o.y = f2bf(g1);
        *reinterpret_cast<ushort2*>(qo + (size_t)i * CC) = o;
    }
}

// -------------------------------------------------------------------------
// Kernel 2a: merged value + oa GEMM (bf16 MFMA), grid.y: 0,1=val  2=oa
// -------------------------------------------------------------------------
__global__ __launch_bounds__(256) void gemm_val_oa(
    const unsigned short* __restrict__ A,
    const unsigned short* __restrict__ Bv, const float* __restrict__ bv_,
    unsigned short* __restrict__ Cv,
    const unsigned short* __restrict__ Bo, const float* __restrict__ bo_,
    float* __restrict__ Co)
{
    __shared__ unsigned short Al[128][72];
    __shared__ unsigned short Bl[128][72];

    bool oam = (blockIdx.y == 2);
    const unsigned short* Bt = oam ? Bo : Bv;
    const float* bias = oam ? bo_ : bv_;
    int bn = oam ? 0 : blockIdx.y * 128;

    int t    = threadIdx.x;
    int bm   = blockIdx.x * 128;
    int wid  = t >> 6;
    int lane = t & 63;
    int wr   = wid >> 1;
    int wc   = wid & 1;
    int lr   = lane & 15;
    int lg   = lane >> 4;

    int srow = t >> 1;
    int sseg = (t & 1) << 5;

    const unsigned short* gA = A + (size_t)(bm + srow) * 256 + sseg;
    const unsigned short* gB = Bt + (size_t)(bn + srow) * 256 + sseg;
    unsigned short* lA = &Al[srow][sseg];
    unsigned short* lB = &Bl[srow][sseg];

    f32x4 acc[4][4] = {};

    for (int kt = 0; kt < 4; ++kt) {
        const unsigned short* ga = gA + kt * 64;
        const unsigned short* gb = gB + kt * 64;
        u32x4 a0 = *(const u32x4*)(ga);
        u32x4 a1 = *(const u32x4*)(ga + 8);
        u32x4 a2 = *(const u32x4*)(ga + 16);
        u32x4 a3 = *(const u32x4*)(ga + 24);
        u32x4 b0 = *(const u32x4*)(gb);
        u32x4 b1 = *(const u32x4*)(gb + 8);
        u32x4 b2 = *(const u32x4*)(gb + 16);
        u32x4 b3 = *(const u32x4*)(gb + 24);
        *(u32x4*)(lA)      = a0;
        *(u32x4*)(lA + 8)  = a1;
        *(u32x4*)(lA + 16) = a2;
        *(u32x4*)(lA + 24) = a3;
        *(u32x4*)(lB)      = b0;
        *(u32x4*)(lB + 8)  = b1;
        *(u32x4*)(lB + 16) = b2;
        *(u32x4*)(lB + 24) = b3;
        __syncthreads();

        #pragma unroll
        for (int kk = 0; kk < 2; ++kk) {
            short8 af[4], bfr[4];
            #pragma unroll
            for (int m = 0; m < 4; ++m)
                af[m] = *(const short8*)(&Al[wr * 64 + m * 16 + lr][kk * 32 + lg * 8]);
            #pragma unroll
            for (int nn = 0; nn < 4; ++nn)
                bfr[nn] = *(const short8*)(&Bl[wc * 64 + nn * 16 + lr][kk * 32 + lg * 8]);
            #pragma unroll
            for (int m = 0; m < 4; ++m)
                #pragma unroll
                for (int nn = 0; nn < 4; ++nn)
                    acc[m][nn] = __builtin_amdgcn_mfma_f32_16x16x32_bf16(
                        af[m], bfr[nn], acc[m][nn], 0, 0, 0);
        }
        __syncthreads();
    }

    float bvv[4];
    #pragma unroll
    for (int nn = 0; nn < 4; ++nn) bvv[nn] = bias[bn + wc * 64 + nn * 16 + lr];

    #pragma unroll
    for (int m = 0; m < 4; ++m) {
        #pragma unroll
        for (int j = 0; j < 4; ++j) {
            int row = bm + wr * 64 + m * 16 + lg * 4 + j;
            if (oam) {
                size_t rbase = (size_t)row * 128;
                #pragma unroll
                for (int nn = 0; nn < 4; ++nn) {
                    int col = wc * 64 + nn * 16 + lr;
                    Co[rbase + col] = acc[m][nn][j] + bvv[nn];
                }
            } else {
                int nb = row >> 14;
                int hw = row & 16383;
                int hh = hw >> 7;
                int ww = hw & 127;
                size_t rbase = (((size_t)nb * HPP + (hh + 1)) * WPP + (ww + 1)) * CC;
                #pragma unroll
                for (int nn = 0; nn < 4; ++nn) {
                    int col = bn + wc * 64 + nn * 16 + lr;
                    Cv[rbase + col] = f2bf(acc[m][nn][j] + bvv[nn]);
                }
            }
        }
    }
}

// -------------------------------------------------------------------------
// Kernel 2b: bf16 MFMA GEMM, row-major fp32 store (output GEMM)
// -------------------------------------------------------------------------
__global__ __launch_bounds__(256) void gemm_mfma_row(
    const unsigned short* __restrict__ A,
    const unsigned short* __restrict__ Bt,
    const float* __restrict__ bias,
    float* __restrict__ C,
    int Nn)
{
    __shared__ unsigned short Al[128][72];
    __shared__ unsigned short Bl[128][72];

    int t    = threadIdx.x;
    int bm   = blockIdx.x * 128;
    int bn   = blockIdx.y * 128;
    int wid  = t >> 6;
    int lane = t & 63;
    int wr   = wid >> 1;
    int wc   = wid & 1;
    int lr   = lane & 15;
    int lg   = lane >> 4;

    int srow = t >> 1;
    int sseg = (t & 1) << 5;

    const unsigned short* gA = A + (size_t)(bm + srow) * 256 + sseg;
    const unsigned short* gB = Bt + (size_t)(bn + srow) * 256 + sseg;
    unsigned short* lA = &Al[srow][sseg];
    unsigned short* lB = &Bl[srow][sseg];

    f32x4 acc[4][4] = {};

    for (int kt = 0; kt < 4; ++kt) {
        const unsigned short* ga = gA + kt * 64;
        const unsigned short* gb = gB + kt * 64;
        u32x4 a0 = *(const u32x4*)(ga);
        u32x4 a1 = *(const u32x4*)(ga + 8);
        u32x4 a2 = *(const u32x4*)(ga + 16);
        u32x4 a3 = *(const u32x4*)(ga + 24);
        u32x4 b0 = *(const u32x4*)(gb);
        u32x4 b1 = *(const u32x4*)(gb + 8);
        u32x4 b2 = *(const u32x4*)(gb + 16);
        u32x4 b3 = *(const u32x4*)(gb + 24);
        *(u32x4*)(lA)      = a0;
        *(u32x4*)(lA + 8)  = a1;
        *(u32x4*)(lA + 16) = a2;
        *(u32x4*)(lA + 24) = a3;
        *(u32x4*)(lB)      = b0;
        *(u32x4*)(lB + 8)  = b1;
        *(u32x4*)(lB + 16) = b2;
        *(u32x4*)(lB + 24) = b3;
        __syncthreads();

        #pragma unroll
        for (int kk = 0; kk < 2; ++kk) {
            short8 af[4], bfr[4];
            #pragma unroll
            for (int m = 0; m < 4; ++m)
                af[m] = *(const short8*)(&Al[wr * 64 + m * 16 + lr][kk * 32 + lg * 8]);
            #pragma unroll
            for (int nn = 0; nn < 4; ++nn)
                bfr[nn] = *(const short8*)(&Bl[wc * 64 + nn * 16 + lr][kk * 32 + lg * 8]);
            #pragma unroll
            for (int m = 0; m < 4; ++m)
                #pragma unroll
                for (int nn = 0; nn < 4; ++nn)
                    acc[m][nn] = __builtin_amdgcn_mfma_f32_16x16x32_bf16(
                        af[m], bfr[nn], acc[m][nn], 0, 0, 0);
        }
        __syncthreads();
    }

    float bvv[4];
    #pragma unroll
    for (int nn = 0; nn < 4; ++nn) bvv[nn] = bias[bn + wc * 64 + nn * 16 + lr];

    #pragma unroll
    for (int m = 0; m < 4; ++m) {
        #pragma unroll
        for (int j = 0; j < 4; ++j) {
            int row = bm + wr * 64 + m * 16 + lg * 4 + j;
            size_t rbase = (size_t)row * Nn;
            #pragma unroll
            for (int nn = 0; nn < 4; ++nn) {
                int col = bn + wc * 64 + nn * 16 + lr;
                C[rbase + col] = acc[m][nn][j] + bvv[nn];
            }
        }
    }
}

// -------------------------------------------------------------------------
// Kernel 3: deformable bilinear sampling + attention-weighted sum
// 8 rows/block; phase 1: 256 threads = (8 rows x 8 heads x 4 points);
// phase 2: thread = 8 channels (ushort8 16B gathers), 32 threads/row.
// -------------------------------------------------------------------------
__global__ __launch_bounds__(256) void sampler_kernel(
    const float* __restrict__ rp,            // (N, LQ, 1, 2)
    const float* __restrict__ oa,            // (N*LQ, 128)
    const unsigned short* __restrict__ vpad, // (N, HP, WP, C) bf16
    unsigned short* __restrict__ outb)       // (N*LQ, C) bf16
{
    __shared__ int4   sIdx[8][4][8];
    __shared__ float4 sW[8][4][8];

    int tid  = threadIdx.x;
    int row0 = blockIdx.x * 8;

    {
        int rl   = tid >> 5;
        int hp   = tid & 31;
        int head = hp >> 2;
        int p    = hp & 3;
        int row  = row0 + rl;

        float ref0 = rp[(size_t)row * 2 + 0];
        float ref1 = rp[(size_t)row * 2 + 1];
        float o0 = oa[(size_t)row * 128 + head * 8 + p * 2 + 0];
        float o1 = oa[(size_t)row * 128 + head * 8 + p * 2 + 1];
        float al = oa[(size_t)row * 128 + 64 + head * 4 + p];
        float a  = 1.0f / (1.0f + __builtin_amdgcn_exp2f(-al * 1.4426950409f));

        float gy = (float)(p >> 1);
        float gx = (float)(p & 1);
        float x = ref0 * WPP + gy + o0 - 0.5f;
        float y = ref1 * HPP + gx + o1 - 0.5f;

        float x0f = floorf(x), y0f = floorf(y);
        int   x0  = (int)x0f,  y0  = (int)y0f;
        float wx1 = x - x0f, wx0 = 1.f - wx1;
        float wy1 = y - y0f, wy0 = 1.f - wy1;
        int x1 = x0 + 1, y1 = y0 + 1;

        bool vx0 = (x0 >= 0) & (x0 < WPP);
        bool vx1 = (x1 >= 0) & (x1 < WPP);
        bool vy0 = (y0 >= 0) & (y0 < HPP);
        bool vy1 = (y1 >= 0) & (y1 < HPP);
        int cx0 = min(max(x0, 0), WPP - 1);
        int cx1 = min(max(x1, 0), WPP - 1);
        int cy0 = min(max(y0, 0), HPP - 1);
        int cy1 = min(max(y1, 0), HPP - 1);

        int4 id;
        id.x = cy0 * WPP + cx0;
        id.y = cy0 * WPP + cx1;
        id.z = cy1 * WPP + cx0;
        id.w = cy1 * WPP + cx1;
        float4 w;
        w.x = (vx0 && vy0) ? a * wx0 * wy0 : 0.f;
        w.y = (vx1 && vy0) ? a * wx1 * wy0 : 0.f;
        w.z = (vx0 && vy1) ? a * wx0 * wy1 : 0.f;
        w.w = (vx1 && vy1) ? a * wx1 * wy1 : 0.f;

        sIdx[rl][p][head] = id;
        sW[rl][p][head]   = w;
    }
    __syncthreads();

    int rl   = tid >> 5;
    int c0   = (tid & 31) * 8;
    int head = (tid & 31) >> 2;
    int row  = row0 + rl;
    int n    = row >> 14;
    const unsigned short* vbase = vpad + (size_t)n * HPP * WPP * CC + c0;

    float acc[8] = {};
    #pragma unroll
    for (int p = 0; p < 4; ++p) {
        int4   id = sIdx[rl][p][head];
        float4 w  = sW[rl][p][head];
        u16x8 g0 = *reinterpret_cast<const u16x8*>(vbase + (size_t)id.x * CC);
        u16x8 g1 = *reinterpret_cast<const u16x8*>(vbase + (size_t)id.y * CC);
        u16x8 g2 = *reinterpret_cast<const u16x8*>(vbase + (size_t)id.z * CC);
        u16x8 g3 = *reinterpret_cast<const u16x8*>(vbase + (size_t)id.w * CC);
        #pragma unroll
        for (int j = 0; j < 8; ++j) {
            acc[j] += w.x * bf2f(g0[j]) + w.y * bf2f(g1[j])
                    + w.z * bf2f(g2[j]) + w.w * bf2f(g3[j]);
        }
    }
    u16x8 o;
    #pragma unroll
    for (int j = 0; j < 8; ++j) o[j] = f2bf(acc[j]);
    *reinterpret_cast<u16x8*>(&outb[(size_t)row * CC + c0]) = o;
}

// -------------------------------------------------------------------------
extern "C" void kernel_launch(void* const* d_in, const int* in_sizes, int n_in,
                              void* d_out, int out_size, void* d_ws, size_t ws_size,
                              hipStream_t stream)
{
    const float* query = (const float*)d_in[0];
    const float* rp    = (const float*)d_in[1];
    const float* dwk   = (const float*)d_in[4];
    const float* dwb   = (const float*)d_in[5];
    const float* lnw   = (const float*)d_in[6];
    const float* lnb   = (const float*)d_in[7];
    const float* Woff  = (const float*)d_in[8];
    const float* boff  = (const float*)d_in[9];
    const float* Wattn = (const float*)d_in[10];
    const float* battn = (const float*)d_in[11];
    const float* Wval  = (const float*)d_in[12];
    const float* bval  = (const float*)d_in[13];
    const float* Wout  = (const float*)d_in[14];
    const float* bout  = (const float*)d_in[15];
    float* out = (float*)d_out;

    const int M = NB * LQ;  // 32768

    // workspace layout (bytes)
    uint8_t* w8 = (uint8_t*)d_ws;
    unsigned short* q_act  = (unsigned short*)w8;                 // 16,777,216
    unsigned short* v_pad  = (unsigned short*)(w8 + 16777216);    // 17,305,600 (bf16)
    float*          oa     = (float*)(w8 + 34082816);             // 16,777,216
    __half*         qh     = (__half*)(w8 + 50860032);            // 16,777,216 (fp16)
    unsigned short* wt_val = (unsigned short*)(w8 + 67637248);    //    131,072
    unsigned short* wt_out = (unsigned short*)(w8 + 67768320);    //    131,072
    unsigned short* wt_oa  = (unsigned short*)(w8 + 67899392);    //     65,536
    float*          b_oa   = (float*)(w8 + 67964928);             //        512
    __half*         kth    = (__half*)(w8 + 67965440);            //     25,088
    unsigned short* out_attn = q_act;  // alias: q_act dead after oa GEMM

    // merged weight prep + border zero + query f32->f16
    prep_kernel<<<5945, 256, 0, stream>>>(
        dwk, Wval, Wout, Woff, boff, Wattn, battn, query,
        kth, wt_val, wt_out, wt_oa, b_oa, v_pad, qh);

    // conv + LN + GELU -> bf16 q_act  (R10 structure + DPP LN reduce)
    {
        dim3 grid(WW / 8, HH, NB);
        conv_ln_gelu_kernel<<<grid, 128, 0, stream>>>(
            qh, kth, dwb, lnw, lnb, q_act);
    }

    // value GEMM (padded bf16 layout) + oa GEMM, one launch
    {
        dim3 grid(M / 128, 3);
        gemm_val_oa<<<grid, 256, 0, stream>>>(
            q_act, wt_val, bval, v_pad, wt_oa, b_oa, oa);
    }

    // sampling + weighted sum -> bf16  (8 rows/block, 16B gathers)
    sampler_kernel<<<M / 8, 256, 0, stream>>>(rp, oa, v_pad, out_attn);

    // output GEMM -> d_out fp32
    {
        dim3 grid(M / 128, 2);
        gemm_mfma_row<<<grid, 256, 0, stream>>>(out_attn, wt_out, bout, out, 256);
    }
}

// Round 16
// 83.225 us; speedup vs baseline: 1.2513x; 1.0148x over previous
//
#include <hip/hip_runtime.h>
#include <hip/hip_bf16.h>
#include <hip/hip_fp16.h>
#include <math.h>

// Problem constants
#define NB   2
#define CC   256
#define HH   128
#define WW   128
#define HPP  130
#define WPP  130
#define LQ   16384   // HH*WW

#define AS1 __attribute__((address_space(1)))
#define AS3 __attribute__((address_space(3)))

typedef __attribute__((ext_vector_type(8))) short short8;
typedef __attribute__((ext_vector_type(8))) unsigned short u16x8;
typedef __attribute__((ext_vector_type(4))) float f32x4;
typedef __attribute__((ext_vector_type(4))) unsigned int u32x4;

static __device__ __forceinline__ unsigned short f2bf(float f) {
    __hip_bfloat16 h = __float2bfloat16(f);
    return __builtin_bit_cast(unsigned short, h);
}
static __device__ __forceinline__ float bf2f(unsigned short u) {
    unsigned int x = ((unsigned int)u) << 16;
    return __builtin_bit_cast(float, x);
}

// branch-free tanh-form GELU: x * sigmoid(1.5957691*(x + 0.044715 x^3))
static __device__ __forceinline__ float gelu_fast(float x) {
    float u = x * x;
    float t = x * fmaf(0.044715f, u, 1.0f);
    float e = __builtin_amdgcn_exp2f(t * 2.3022083f);
    float r = __builtin_amdgcn_rcpf(e + 1.0f);
    return x - x * r;
}

// ---- DPP wave-64 sum reduction (VALU pipe, no LDS) ----------------------
template <int CTRL, int RMASK, int BMASK>
static __device__ __forceinline__ float dpp_add(float x) {
    int s = __builtin_bit_cast(int, x);
    int d = __builtin_amdgcn_update_dpp(0, s, CTRL, RMASK, BMASK, true);
    return x + __builtin_bit_cast(float, d);
}
static __device__ __forceinline__ float wave_sum_lane63(float x) {
    x = dpp_add<0x111, 0xf, 0xf>(x);   // row_shr:1
    x = dpp_add<0x112, 0xf, 0xf>(x);   // row_shr:2
    x = dpp_add<0x114, 0xf, 0xe>(x);   // row_shr:4
    x = dpp_add<0x118, 0xf, 0xc>(x);   // row_shr:8
    x = dpp_add<0x142, 0xa, 0xf>(x);   // row_bcast:15
    x = dpp_add<0x143, 0xc, 0xf>(x);   // row_bcast:31
    return x;                          // valid in lane 63
}

// ---- async global->LDS stage of a 128x64 bf16 tile, XOR-swizzled --------
// LDS is linear [128][64]; logical (row, elem e) stored at elem
// e ^ ((row&7)<<3).  Writer: lane reads global col 8*((lane&7)^(row&7)),
// HW writes lane*16 bytes from wave-uniform base (8 rows / instruction).
// Reader applies the same XOR.  Read banks: 2-way (free); writes: linear.
static __device__ __forceinline__ void gload_tile_swz(
    const unsigned short* __restrict__ g_base,  // tile_row0*256 + kt*64
    unsigned short* lds_base,                   // &Tile[0][0]
    int wid, int lane)
{
    #pragma unroll
    for (int i = 0; i < 4; ++i) {
        int r0  = wid * 32 + i * 8;
        int r   = r0 + (lane >> 3);
        int col = ((lane & 7) ^ (r & 7)) << 3;   // bf16 elements
        const unsigned short* g = g_base + (size_t)r * 256 + col;
        unsigned short* l = lds_base + (size_t)r0 * 64;
        __builtin_amdgcn_global_load_lds(
            (const AS1 unsigned int*)g, (AS3 unsigned int*)l, 16, 0, 0);
    }
}

// -------------------------------------------------------------------------
// Kernel A: merged weight prep + v_pad border zero + query fp32->fp16.
// -------------------------------------------------------------------------
__global__ __launch_bounds__(256) void prep_kernel(
    const float* __restrict__ dwk,
    const float* __restrict__ Wval,
    const float* __restrict__ Wout,
    const float* __restrict__ Woff, const float* __restrict__ boff,
    const float* __restrict__ Wattn, const float* __restrict__ battn,
    const float* __restrict__ query,
    __half* __restrict__ kth,
    unsigned short* __restrict__ wt_val,
    unsigned short* __restrict__ wt_out,
    unsigned short* __restrict__ wt_oa,
    float* __restrict__ b_oa,
    unsigned short* __restrict__ vpad,
    __half* __restrict__ qh)
{
    int b = blockIdx.x;
    int t = threadIdx.x;
    if (b < 49) {
        kth[b * CC + t] = __float2half(dwk[t * 49 + b]);
    } else if (b < 305) {
        int k = b - 49;
        wt_val[(size_t)t * 256 + k] = f2bf(Wval[(size_t)k * 256 + t]);
    } else if (b < 561) {
        int k = b - 305;
        wt_out[(size_t)t * 256 + k] = f2bf(Wout[(size_t)k * 256 + t]);
    } else if (b < 817) {
        int k = b - 561;
        if (t < 128) {
            float v = 0.f, bb = 0.f;
            if (t < 64)      { v = Woff[(size_t)k * 64 + t];        bb = boff[t]; }
            else if (t < 96) { v = Wattn[(size_t)k * 32 + (t - 64)]; bb = battn[t - 64]; }
            wt_oa[(size_t)t * 256 + k] = f2bf(v);
            if (k == 0) b_oa[t] = bb;
        }
    } else if (b < 1849) {
        int bb = b - 817;
        int n = (bb >= 516) ? 1 : 0;
        int i = bb - n * 516;
        int y, x;
        if (i < 130)      { y = 0;           x = i; }
        else if (i < 260) { y = 129;         x = i - 130; }
        else if (i < 388) { y = i - 260 + 1; x = 0; }
        else              { y = i - 388 + 1; x = 129; }
        vpad[(((size_t)n * HPP + y) * WPP + x) * CC + t] = 0;
    } else {
        size_t idx0 = (size_t)(b - 1849) * 2048 + (size_t)t * 8;
        const float4* src = reinterpret_cast<const float4*>(query + idx0);
        float4 f0 = src[0];
        float4 f1 = src[1];
        __half2 h0 = __floats2half2_rn(f0.x, f0.y);
        __half2 h1 = __floats2half2_rn(f0.z, f0.w);
        __half2 h2 = __floats2half2_rn(f1.x, f1.y);
        __half2 h3 = __floats2half2_rn(f1.z, f1.w);
        u32x4 o;
        o.x = __builtin_bit_cast(unsigned int, h0);
        o.y = __builtin_bit_cast(unsigned int, h1);
        o.z = __builtin_bit_cast(unsigned int, h2);
        o.w = __builtin_bit_cast(unsigned int, h3);
        *reinterpret_cast<u32x4*>(qh + idx0) = o;
    }
}

// -------------------------------------------------------------------------
// Kernel 1: fused depthwise 7x7 conv (fp16x2) + bias + channel-LN + GELU.
// R10 structure; DPP LN reduce (R15, equal-best).
// -------------------------------------------------------------------------
__global__ __launch_bounds__(128) void conv_ln_gelu_kernel(
    const __half* __restrict__ qh,    // (N, LQ, C) fp16
    const __half* __restrict__ kth,   // (49, C) fp16
    const float* __restrict__ kbias,
    const float* __restrict__ lnw,
    const float* __restrict__ lnb,
    unsigned short* __restrict__ qact) // (N, LQ, C) bf16
{
    int t  = threadIdx.x;             // 0..127 -> channels 2t, 2t+1
    int w0 = blockIdx.x * 8;
    int h  = blockIdx.y;
    int n  = blockIdx.z;

    const __half2* qn  = reinterpret_cast<const __half2*>(qh + (size_t)n * LQ * CC) + t;
    const __half2* ktc = reinterpret_cast<const __half2*>(kth) + t;

    __half2 acc[8];
    #pragma unroll
    for (int i = 0; i < 8; ++i) acc[i] = __half2(0.f, 0.f);

    if (w0 >= 8 && w0 <= 112 && h >= 3 && h <= 124) {
        #pragma unroll
        for (int ky = 0; ky < 7; ++ky) {
            const __half2* qrow = qn + ((size_t)(h + ky - 3) * WW + (w0 - 3)) * 128;
            __half2 wt[7];
            #pragma unroll
            for (int kx = 0; kx < 7; ++kx)
                wt[kx] = ktc[(ky * 7 + kx) * 128];
            __half2 in[14];
            #pragma unroll
            for (int j = 0; j < 14; ++j)
                in[j] = qrow[(size_t)j * 128];
            #pragma unroll
            for (int i = 0; i < 8; ++i)
                #pragma unroll
                for (int kx = 0; kx < 7; ++kx)
                    acc[i] = __hfma2(in[i + kx], wt[kx], acc[i]);
        }
    } else {
        #pragma unroll
        for (int ky = 0; ky < 7; ++ky) {
            int iy = h + ky - 3;
            if (iy < 0 || iy >= HH) continue;
            const __half2* qrow = qn + (size_t)iy * WW * 128;
            __half2 wt[7];
            #pragma unroll
            for (int kx = 0; kx < 7; ++kx)
                wt[kx] = ktc[(ky * 7 + kx) * 128];
            __half2 in[14];
            #pragma unroll
            for (int j = 0; j < 14; ++j) {
                int ix = w0 - 3 + j;
                in[j] = (ix >= 0 && ix < WW) ? qrow[(size_t)ix * 128]
                                             : __half2(0.f, 0.f);
            }
            #pragma unroll
            for (int i = 0; i < 8; ++i)
                #pragma unroll
                for (int kx = 0; kx < 7; ++kx)
                    acc[i] = __hfma2(in[i + kx], wt[kx], acc[i]);
        }
    }

    float b0 = kbias[2 * t];
    float b1 = kbias[2 * t + 1];
    float a0[8], a1[8];
    #pragma unroll
    for (int i = 0; i < 8; ++i) {
        a0[i] = __low2float(acc[i])  + b0;
        a1[i] = __high2float(acc[i]) + b1;
    }

    __shared__ float lsum[8][2];
    __shared__ float lsq[8][2];
    int lane = t & 63;
    int wv   = t >> 6;

    #pragma unroll
    for (int i = 0; i < 8; ++i) {
        float s  = wave_sum_lane63(a0[i] + a1[i]);
        float sq = wave_sum_lane63(a0[i] * a0[i] + a1[i] * a1[i]);
        if (lane == 63) { lsum[i][wv] = s; lsq[i][wv] = sq; }
    }
    __syncthreads();

    float lw0 = lnw[2 * t], lw1 = lnw[2 * t + 1];
    float lb0 = lnb[2 * t], lb1 = lnb[2 * t + 1];
    unsigned short* qo = qact + (((size_t)n * LQ) + (size_t)h * WW + w0) * CC + 2 * t;

    #pragma unroll
    for (int i = 0; i < 8; ++i) {
        float s   = lsum[i][0] + lsum[i][1];
        float sq  = lsq[i][0]  + lsq[i][1];
        float mu  = s * (1.0f / 256.0f);
        float var = sq * (1.0f / 256.0f) - mu * mu;
        float inv = rsqrtf(var + 1e-5f);
        float g0 = gelu_fast((a0[i] - mu) * inv * lw0 + lb0);
        float g1 = gelu_fast((a1[i] - mu) * inv * lw1 + lb1);
        ushort2 o;
        o.x = f2bf(g0);
        o.y = f2bf(g1);
        *reinterpret_cast<ushort2*>(qo + (size_t)i * CC) = o;
    }
}

// -------------------------------------------------------------------------
// Kernel 2a: merged value + oa GEMM (bf16 MFMA), grid.y: 0,1=val  2=oa
// Staging via global_load_lds (16B) + XOR-swizzled linear LDS [128][64].
// -------------------------------------------------------------------------
__global__ __launch_bounds__(256) void gemm_val_oa(
    const unsigned short* __restrict__ A,
    const unsigned short* __restrict__ Bv, const float* __restrict__ bv_,
    unsigned short* __restrict__ Cv,
    const unsigned short* __restrict__ Bo, const float* __restrict__ bo_,
    float* __restrict__ Co)
{
    __shared__ unsigned short Al[128][64];
    __shared__ unsigned short Bl[128][64];

    bool oam = (blockIdx.y == 2);
    const unsigned short* Bt = oam ? Bo : Bv;
    const float* bias = oam ? bo_ : bv_;
    int bn = oam ? 0 : blockIdx.y * 128;

    int t    = threadIdx.x;
    int bm   = blockIdx.x * 128;
    int wid  = t >> 6;
    int lane = t & 63;
    int wr   = wid >> 1;
    int wc   = wid & 1;
    int lr   = lane & 15;
    int lg   = lane >> 4;

    f32x4 acc[4][4] = {};

    for (int kt = 0; kt < 4; ++kt) {
        gload_tile_swz(A  + (size_t)bm * 256 + kt * 64, &Al[0][0], wid, lane);
        gload_tile_swz(Bt + (size_t)bn * 256 + kt * 64, &Bl[0][0], wid, lane);
        __syncthreads();

        #pragma unroll
        for (int kk = 0; kk < 2; ++kk) {
            short8 af[4], bfr[4];
            #pragma unroll
            for (int m = 0; m < 4; ++m) {
                int R = wr * 64 + m * 16 + lr;
                af[m] = *(const short8*)(&Al[R][(kk * 32 + lg * 8) ^ ((R & 7) << 3)]);
            }
            #pragma unroll
            for (int nn = 0; nn < 4; ++nn) {
                int R = wc * 64 + nn * 16 + lr;
                bfr[nn] = *(const short8*)(&Bl[R][(kk * 32 + lg * 8) ^ ((R & 7) << 3)]);
            }
            #pragma unroll
            for (int m = 0; m < 4; ++m)
                #pragma unroll
                for (int nn = 0; nn < 4; ++nn)
                    acc[m][nn] = __builtin_amdgcn_mfma_f32_16x16x32_bf16(
                        af[m], bfr[nn], acc[m][nn], 0, 0, 0);
        }
        __syncthreads();
    }

    float bvv[4];
    #pragma unroll
    for (int nn = 0; nn < 4; ++nn) bvv[nn] = bias[bn + wc * 64 + nn * 16 + lr];

    #pragma unroll
    for (int m = 0; m < 4; ++m) {
        #pragma unroll
        for (int j = 0; j < 4; ++j) {
            int row = bm + wr * 64 + m * 16 + lg * 4 + j;
            if (oam) {
                size_t rbase = (size_t)row * 128;
                #pragma unroll
                for (int nn = 0; nn < 4; ++nn) {
                    int col = wc * 64 + nn * 16 + lr;
                    Co[rbase + col] = acc[m][nn][j] + bvv[nn];
                }
            } else {
                int nb = row >> 14;
                int hw = row & 16383;
                int hh = hw >> 7;
                int ww = hw & 127;
                size_t rbase = (((size_t)nb * HPP + (hh + 1)) * WPP + (ww + 1)) * CC;
                #pragma unroll
                for (int nn = 0; nn < 4; ++nn) {
                    int col = bn + wc * 64 + nn * 16 + lr;
                    Cv[rbase + col] = f2bf(acc[m][nn][j] + bvv[nn]);
                }
            }
        }
    }
}

// -------------------------------------------------------------------------
// Kernel 2b: bf16 MFMA GEMM, row-major fp32 store (output GEMM)
// Same global_load_lds + swizzle staging.
// -------------------------------------------------------------------------
__global__ __launch_bounds__(256) void gemm_mfma_row(
    const unsigned short* __restrict__ A,
    const unsigned short* __restrict__ Bt,
    const float* __restrict__ bias,
    float* __restrict__ C,
    int Nn)
{
    __shared__ unsigned short Al[128][64];
    __shared__ unsigned short Bl[128][64];

    int t    = threadIdx.x;
    int bm   = blockIdx.x * 128;
    int bn   = blockIdx.y * 128;
    int wid  = t >> 6;
    int lane = t & 63;
    int wr   = wid >> 1;
    int wc   = wid & 1;
    int lr   = lane & 15;
    int lg   = lane >> 4;

    f32x4 acc[4][4] = {};

    for (int kt = 0; kt < 4; ++kt) {
        gload_tile_swz(A  + (size_t)bm * 256 + kt * 64, &Al[0][0], wid, lane);
        gload_tile_swz(Bt + (size_t)bn * 256 + kt * 64, &Bl[0][0], wid, lane);
        __syncthreads();

        #pragma unroll
        for (int kk = 0; kk < 2; ++kk) {
            short8 af[4], bfr[4];
            #pragma unroll
            for (int m = 0; m < 4; ++m) {
                int R = wr * 64 + m * 16 + lr;
                af[m] = *(const short8*)(&Al[R][(kk * 32 + lg * 8) ^ ((R & 7) << 3)]);
            }
            #pragma unroll
            for (int nn = 0; nn < 4; ++nn) {
                int R = wc * 64 + nn * 16 + lr;
                bfr[nn] = *(const short8*)(&Bl[R][(kk * 32 + lg * 8) ^ ((R & 7) << 3)]);
            }
            #pragma unroll
            for (int m = 0; m < 4; ++m)
                #pragma unroll
                for (int nn = 0; nn < 4; ++nn)
                    acc[m][nn] = __builtin_amdgcn_mfma_f32_16x16x32_bf16(
                        af[m], bfr[nn], acc[m][nn], 0, 0, 0);
        }
        __syncthreads();
    }

    float bvv[4];
    #pragma unroll
    for (int nn = 0; nn < 4; ++nn) bvv[nn] = bias[bn + wc * 64 + nn * 16 + lr];

    #pragma unroll
    for (int m = 0; m < 4; ++m) {
        #pragma unroll
        for (int j = 0; j < 4; ++j) {
            int row = bm + wr * 64 + m * 16 + lg * 4 + j;
            size_t rbase = (size_t)row * Nn;
            #pragma unroll
            for (int nn = 0; nn < 4; ++nn) {
                int col = bn + wc * 64 + nn * 16 + lr;
                C[rbase + col] = acc[m][nn][j] + bvv[nn];
            }
        }
    }
}

// -------------------------------------------------------------------------
// Kernel 3: deformable bilinear sampling + attention-weighted sum
// -------------------------------------------------------------------------
__global__ __launch_bounds__(256) void sampler_kernel(
    const float* __restrict__ rp,            // (N, LQ, 1, 2)
    const float* __restrict__ oa,            // (N*LQ, 128)
    const unsigned short* __restrict__ vpad, // (N, HP, WP, C) bf16
    unsigned short* __restrict__ outb)       // (N*LQ, C) bf16
{
    __shared__ int4   sIdx[8][4][8];
    __shared__ float4 sW[8][4][8];

    int tid  = threadIdx.x;
    int row0 = blockIdx.x * 8;

    {
        int rl   = tid >> 5;
        int hp   = tid & 31;
        int head = hp >> 2;
        int p    = hp & 3;
        int row  = row0 + rl;

        float ref0 = rp[(size_t)row * 2 + 0];
        float ref1 = rp[(size_t)row * 2 + 1];
        float o0 = oa[(size_t)row * 128 + head * 8 + p * 2 + 0];
        float o1 = oa[(size_t)row * 128 + head * 8 + p * 2 + 1];
        float al = oa[(size_t)row * 128 + 64 + head * 4 + p];
        float a  = 1.0f / (1.0f + __builtin_amdgcn_exp2f(-al * 1.4426950409f));

        float gy = (float)(p >> 1);
        float gx = (float)(p & 1);
        float x = ref0 * WPP + gy + o0 - 0.5f;
        float y = ref1 * HPP + gx + o1 - 0.5f;

        float x0f = floorf(x), y0f = floorf(y);
        int   x0  = (int)x0f,  y0  = (int)y0f;
        float wx1 = x - x0f, wx0 = 1.f - wx1;
        float wy1 = y - y0f, wy0 = 1.f - wy1;
        int x1 = x0 + 1, y1 = y0 + 1;

        bool vx0 = (x0 >= 0) & (x0 < WPP);
        bool vx1 = (x1 >= 0) & (x1 < WPP);
        bool vy0 = (y0 >= 0) & (y0 < HPP);
        bool vy1 = (y1 >= 0) & (y1 < HPP);
        int cx0 = min(max(x0, 0), WPP - 1);
        int cx1 = min(max(x1, 0), WPP - 1);
        int cy0 = min(max(y0, 0), HPP - 1);
        int cy1 = min(max(y1, 0), HPP - 1);

        int4 id;
        id.x = cy0 * WPP + cx0;
        id.y = cy0 * WPP + cx1;
        id.z = cy1 * WPP + cx0;
        id.w = cy1 * WPP + cx1;
        float4 w;
        w.x = (vx0 && vy0) ? a * wx0 * wy0 : 0.f;
        w.y = (vx1 && vy0) ? a * wx1 * wy0 : 0.f;
        w.z = (vx0 && vy1) ? a * wx0 * wy1 : 0.f;
        w.w = (vx1 && vy1) ? a * wx1 * wy1 : 0.f;

        sIdx[rl][p][head] = id;
        sW[rl][p][head]   = w;
    }
    __syncthreads();

    int rl   = tid >> 5;
    int c0   = (tid & 31) * 8;
    int head = (tid & 31) >> 2;
    int row  = row0 + rl;
    int n    = row >> 14;
    const unsigned short* vbase = vpad + (size_t)n * HPP * WPP * CC + c0;

    float acc[8] = {};
    #pragma unroll
    for (int p = 0; p < 4; ++p) {
        int4   id = sIdx[rl][p][head];
        float4 w  = sW[rl][p][head];
        u16x8 g0 = *reinterpret_cast<const u16x8*>(vbase + (size_t)id.x * CC);
        u16x8 g1 = *reinterpret_cast<const u16x8*>(vbase + (size_t)id.y * CC);
        u16x8 g2 = *reinterpret_cast<const u16x8*>(vbase + (size_t)id.z * CC);
        u16x8 g3 = *reinterpret_cast<const u16x8*>(vbase + (size_t)id.w * CC);
        #pragma unroll
        for (int j = 0; j < 8; ++j) {
            acc[j] += w.x * bf2f(g0[j]) + w.y * bf2f(g1[j])
                    + w.z * bf2f(g2[j]) + w.w * bf2f(g3[j]);
        }
    }
    u16x8 o;
    #pragma unroll
    for (int j = 0; j < 8; ++j) o[j] = f2bf(acc[j]);
    *reinterpret_cast<u16x8*>(&outb[(size_t)row * CC + c0]) = o;
}

// -------------------------------------------------------------------------
extern "C" void kernel_launch(void* const* d_in, const int* in_sizes, int n_in,
                              void* d_out, int out_size, void* d_ws, size_t ws_size,
                              hipStream_t stream)
{
    const float* query = (const float*)d_in[0];
    const float* rp    = (const float*)d_in[1];
    const float* dwk   = (const float*)d_in[4];
    const float* dwb   = (const float*)d_in[5];
    const float* lnw   = (const float*)d_in[6];
    const float* lnb   = (const float*)d_in[7];
    const float* Woff  = (const float*)d_in[8];
    const float* boff  = (const float*)d_in[9];
    const float* Wattn = (const float*)d_in[10];
    const float* battn = (const float*)d_in[11];
    const float* Wval  = (const float*)d_in[12];
    const float* bval  = (const float*)d_in[13];
    const float* Wout  = (const float*)d_in[14];
    const float* bout  = (const float*)d_in[15];
    float* out = (float*)d_out;

    const int M = NB * LQ;  // 32768

    // workspace layout (bytes)
    uint8_t* w8 = (uint8_t*)d_ws;
    unsigned short* q_act  = (unsigned short*)w8;                 // 16,777,216
    unsigned short* v_pad  = (unsigned short*)(w8 + 16777216);    // 17,305,600 (bf16)
    float*          oa     = (float*)(w8 + 34082816);             // 16,777,216
    __half*         qh     = (__half*)(w8 + 50860032);            // 16,777,216 (fp16)
    unsigned short* wt_val = (unsigned short*)(w8 + 67637248);    //    131,072
    unsigned short* wt_out = (unsigned short*)(w8 + 67768320);    //    131,072
    unsigned short* wt_oa  = (unsigned short*)(w8 + 67899392);    //     65,536
    float*          b_oa   = (float*)(w8 + 67964928);             //        512
    __half*         kth    = (__half*)(w8 + 67965440);            //     25,088
    unsigned short* out_attn = q_act;  // alias: q_act dead after oa GEMM

    // merged weight prep + border zero + query f32->f16
    prep_kernel<<<5945, 256, 0, stream>>>(
        dwk, Wval, Wout, Woff, boff, Wattn, battn, query,
        kth, wt_val, wt_out, wt_oa, b_oa, v_pad, qh);

    // conv + LN + GELU -> bf16 q_act
    {
        dim3 grid(WW / 8, HH, NB);
        conv_ln_gelu_kernel<<<grid, 128, 0, stream>>>(
            qh, kth, dwb, lnw, lnb, q_act);
    }

    // value GEMM (padded bf16 layout) + oa GEMM, one launch
    {
        dim3 grid(M / 128, 3);
        gemm_val_oa<<<grid, 256, 0, stream>>>(
            q_act, wt_val, bval, v_pad, wt_oa, b_oa, oa);
    }

    // sampling + weighted sum -> bf16
    sampler_kernel<<<M / 8, 256, 0, stream>>>(rp, oa, v_pad, out_attn);

    // output GEMM -> d_out fp32
    {
        dim3 grid(M / 128, 2);
        gemm_mfma_row<<<grid, 256, 0, stream>>>(out_attn, wt_out, bout, out, 256);
    }
}